// Round 2
// baseline (26096.924 us; speedup 1.0000x reference)
//
#include <hip/hip_runtime.h>
#include <math.h>

#define T_    256
#define D_    1024
#define C_    512
#define H_    4
#define DH_   128
#define BNB   160            // b*ncrops = 16*10
#define CHUNK 8              // bn sequences per pipeline pass
#define MR    (CHUNK * T_)   // 2048 rows per chunk
#define LEPS  1e-5f
#define INV_E 0.36787944117144233f
#define SCALE_ 0.08838834764831845f   // 1/sqrt(128)

// ---------------------------------------------------------------- zero fill
__global__ void zero_k(float* __restrict__ p, int n) {
    int i = blockIdx.x * 256 + threadIdx.x;
    if (i < n) p[i] = 0.0f;
}

// ------------------------------------------- W_emb (C,1024,3) -> Wt (3072,C)
__global__ void wemb_transpose_k(const float* __restrict__ W, float* __restrict__ Wt) {
    int idx = blockIdx.x * 256 + threadIdx.x;
    if (idx >= 3072 * C_) return;
    int k = idx / C_, c = idx % C_;
    int dt = k / D_, i = k % D_;
    Wt[idx] = W[(size_t)c * 3072 + i * 3 + dt];
}

// -------------------------------- s[j] = sum_k exp(-|j-k|/e)  (a2 col sums)
__global__ void a2_colsum_k(float* __restrict__ s) {
    int j = threadIdx.x;
    float acc = 0.0f;
    for (int k = 0; k < T_; k++) acc += expf(-fabsf((float)(j - k)) * INV_E);
    s[j] = acc;
}

// ---------------------------------------------------------------- LayerNorm
__global__ __launch_bounds__(256)
void ln_k(const float* __restrict__ X, const float* __restrict__ g,
          const float* __restrict__ b, float* __restrict__ Z) {
    int row = blockIdx.x;
    int tid = threadIdx.x;
    const float* xr = X + (size_t)row * C_;
    float x0 = xr[tid], x1 = xr[tid + 256];
    __shared__ float red[256];
    red[tid] = x0 + x1;
    __syncthreads();
    for (int s = 128; s >= 1; s >>= 1) {
        if (tid < s) red[tid] += red[tid + s];
        __syncthreads();
    }
    float mean = red[0] * (1.0f / C_);
    __syncthreads();
    float d0 = x0 - mean, d1 = x1 - mean;
    red[tid] = d0 * d0 + d1 * d1;
    __syncthreads();
    for (int s = 128; s >= 1; s >>= 1) {
        if (tid < s) red[tid] += red[tid + s];
        __syncthreads();
    }
    float rinv = rsqrtf(red[0] * (1.0f / C_) + LEPS);
    float* zr = Z + (size_t)row * C_;
    zr[tid]       = d0 * rinv * g[tid]       + b[tid];
    zr[tid + 256] = d1 * rinv * g[tid + 256] + b[tid + 256];
}

// ------------------------------------------------------------ tiled SGEMM
// C = A(MxK) @ B(KxN) [+bias(col)] [act: 1=gelu] [+R]  (M%64==0,N%64==0,K%16==0)
__global__ __launch_bounds__(256)
void sgemm_k(const float* __restrict__ A, const float* __restrict__ B,
             const float* __restrict__ bias, const float* __restrict__ R,
             float* __restrict__ C, int M, int N, int K, int act) {
    __shared__ float As[16][65];
    __shared__ float Bs[16][64];
    const int tid = threadIdx.x;
    const int m0 = blockIdx.y * 64;
    const int n0 = blockIdx.x * 64;
    const int tm = (tid >> 4) << 2;
    const int tn = (tid & 15) << 2;
    const int a_k = tid & 15;
    const int a_m = tid >> 4;
    const int b_n = tid & 63;
    const int b_k = tid >> 6;
    float acc[4][4] = {{0.0f}};
    for (int k0 = 0; k0 < K; k0 += 16) {
#pragma unroll
        for (int i = 0; i < 4; i++) {
            int m = a_m + i * 16;
            As[a_k][m] = A[(size_t)(m0 + m) * K + k0 + a_k];
        }
#pragma unroll
        for (int i = 0; i < 4; i++) {
            int k = b_k + i * 4;
            Bs[k][b_n] = B[(size_t)(k0 + k) * N + n0 + b_n];
        }
        __syncthreads();
#pragma unroll
        for (int kk = 0; kk < 16; kk++) {
            float a[4], bb[4];
#pragma unroll
            for (int i = 0; i < 4; i++) a[i] = As[kk][tm + i];
#pragma unroll
            for (int j = 0; j < 4; j++) bb[j] = Bs[kk][tn + j];
#pragma unroll
            for (int i = 0; i < 4; i++)
#pragma unroll
                for (int j = 0; j < 4; j++) acc[i][j] += a[i] * bb[j];
        }
        __syncthreads();
    }
#pragma unroll
    for (int i = 0; i < 4; i++) {
        int row = m0 + tm + i;
#pragma unroll
        for (int j = 0; j < 4; j++) {
            int col = n0 + tn + j;
            float v = acc[i][j];
            if (bias) v += bias[col];
            if (act == 1) v = v * 0.5f * (1.0f + erff(v * 0.70710678118654752f));
            if (R) v += R[(size_t)row * N + col];
            C[(size_t)row * N + col] = v;
        }
    }
}

// ------------------------------------------- conv1d(k=3,pad=1)+ReLU as GEMM
__global__ __launch_bounds__(256)
void conv_emb_k(const float* __restrict__ X, const float* __restrict__ Wt,
                const float* __restrict__ bias, float* __restrict__ Hout) {
    __shared__ float As[16][65];
    __shared__ float Bs[16][64];
    const int tid = threadIdx.x;
    const int bn = blockIdx.z;                 // local bn within chunk
    const int t0 = blockIdx.y * 64;
    const int n0 = blockIdx.x * 64;
    const float* Xb = X + (size_t)bn * T_ * D_;
    const int tm = (tid >> 4) << 2;
    const int tn = (tid & 15) << 2;
    const int a_k = tid & 15;
    const int a_m = tid >> 4;
    const int b_n = tid & 63;
    const int b_k = tid >> 6;
    float acc[4][4] = {{0.0f}};
    for (int k0 = 0; k0 < 3072; k0 += 16) {
#pragma unroll
        for (int i = 0; i < 4; i++) {
            int m = a_m + i * 16;
            int pos = (t0 + m - 1) * D_ + k0 + a_k;
            As[a_k][m] = (pos >= 0 && pos < T_ * D_) ? Xb[pos] : 0.0f;
        }
#pragma unroll
        for (int i = 0; i < 4; i++) {
            int k = b_k + i * 4;
            Bs[k][b_n] = Wt[(size_t)(k0 + k) * C_ + n0 + b_n];
        }
        __syncthreads();
#pragma unroll
        for (int kk = 0; kk < 16; kk++) {
            float a[4], bb[4];
#pragma unroll
            for (int i = 0; i < 4; i++) a[i] = As[kk][tm + i];
#pragma unroll
            for (int j = 0; j < 4; j++) bb[j] = Bs[kk][tn + j];
#pragma unroll
            for (int i = 0; i < 4; i++)
#pragma unroll
                for (int j = 0; j < 4; j++) acc[i][j] += a[i] * bb[j];
        }
        __syncthreads();
    }
#pragma unroll
    for (int i = 0; i < 4; i++) {
        int t = t0 + tm + i;
#pragma unroll
        for (int j = 0; j < 4; j++) {
            int c = n0 + tn + j;
            float v = fmaxf(acc[i][j] + bias[c], 0.0f);
            Hout[((size_t)bn * T_ + t) * C_ + c] = v;
        }
    }
}

// ------------------------------------------------ dual attention, per query
__global__ __launch_bounds__(256)
void attn_k(const float* __restrict__ qkvt, const float* __restrict__ s256,
            float* __restrict__ O) {
    const int i  = blockIdx.x;
    const int h  = blockIdx.y;
    const int bn = blockIdx.z;                 // local bn within chunk
    const int tid = threadIdx.x;
    __shared__ __align__(16) float qi[DH_];
    __shared__ float p[T_];
    __shared__ float w[T_];
    __shared__ float red[256];
    const float* base = qkvt + (size_t)bn * T_ * 2048;
    if (tid < DH_) qi[tid] = base[(size_t)i * 2048 + h * DH_ + tid];
    __syncthreads();
    const int j = tid;
    const float4* k4 = (const float4*)(base + (size_t)j * 2048 + 512 + h * DH_);
    const float4* q4 = (const float4*)qi;
    float sc = 0.0f;
#pragma unroll
    for (int u = 0; u < DH_ / 4; u++) {
        float4 kv = k4[u], qv = q4[u];
        sc += kv.x * qv.x + kv.y * qv.y + kv.z * qv.z + kv.w * qv.w;
    }
    sc *= SCALE_;
    w[j] = expf(-fabsf((float)(i - j)) * INV_E) / s256[j];
    red[tid] = sc;
    __syncthreads();
    for (int s = 128; s >= 1; s >>= 1) {
        if (tid < s) red[tid] = fmaxf(red[tid], red[tid + s]);
        __syncthreads();
    }
    float mx = red[0];
    __syncthreads();
    float e = expf(sc - mx);
    red[tid] = e;
    __syncthreads();
    for (int s = 128; s >= 1; s >>= 1) {
        if (tid < s) red[tid] += red[tid + s];
        __syncthreads();
    }
    p[tid] = e / red[0];
    __syncthreads();
    float acc = 0.0f;
    if (tid < DH_) {
        const float* vcol = base + 1024 + h * DH_ + tid;
        for (int jj = 0; jj < T_; jj++) acc += p[jj] * vcol[(size_t)jj * 2048];
        O[((size_t)bn * T_ + i) * 1024 + h * 256 + tid] = acc;
    } else {
        int d = tid - DH_;
        const float* tcol = base + 1536 + h * DH_ + d;
        for (int jj = 0; jj < T_; jj++) acc += w[jj] * tcol[(size_t)jj * 2048];
        O[((size_t)bn * T_ + i) * 1024 + h * 256 + 128 + d] = acc;
    }
}

// --------------------------------------------------- fused head, 1 wave/(bn,t)
__global__ __launch_bounds__(64)
void head_k(const float* __restrict__ Hf, int bn_base,
            const float* __restrict__ c1W, const float* __restrict__ c1b,
            const float* __restrict__ g1, const float* __restrict__ b1,
            const float* __restrict__ m1, const float* __restrict__ v1,
            const float* __restrict__ c2W, const float* __restrict__ c2b,
            const float* __restrict__ g2, const float* __restrict__ b2,
            const float* __restrict__ m2, const float* __restrict__ v2,
            const float* __restrict__ c3W, const float* __restrict__ c3b,
            float* __restrict__ sum_dist, float* __restrict__ sum_score) {
    const int t = blockIdx.x, bn = blockIdx.y;   // bn local to chunk
    const int tid = threadIdx.x;
    __shared__ float hr[C_];
    __shared__ float x1[32], y1[32], x2[16], y2[16];
    const float* row = Hf + ((size_t)bn * T_ + t) * C_;
    for (int u = tid; u < C_; u += 64) hr[u] = row[u];
    __syncthreads();
    if (tid < 32) {
        float acc = c1b[tid];
        const float* wr = c1W + (size_t)tid * C_;
        for (int c = 0; c < C_; c++) acc += wr[c] * hr[c];
        x1[tid] = acc;
        y1[tid] = fmaxf(0.0f, (acc - m1[tid]) * rsqrtf(v1[tid] + LEPS) * g1[tid] + b1[tid]);
    }
    __syncthreads();
    if (tid < 16) {
        float acc = c2b[tid];
        for (int c = 0; c < 32; c++) acc += c2W[tid * 32 + c] * y1[c];
        x2[tid] = acc;
        y2[tid] = fmaxf(0.0f, (acc - m2[tid]) * rsqrtf(v2[tid] + LEPS) * g2[tid] + b2[tid]);
    }
    __syncthreads();
    if (tid == 0) {
        float d1 = 0.0f;
        for (int c = 0; c < 32; c++) { float dd = x1[c] - m1[c]; d1 += dd * dd / v1[c]; }
        float d2 = 0.0f;
        for (int c = 0; c < 16; c++) { float dd = x2[c] - m2[c]; d2 += dd * dd / v2[c]; }
        float dist = sqrtf(d1) + sqrtf(d2);
        float sc = c3b[0];
        for (int c = 0; c < 16; c++) sc += c3W[c] * y2[c];
        sc = 1.0f / (1.0f + expf(-sc));
        int b = (bn_base + bn) / 10;
        atomicAdd(&sum_dist[b * T_ + t], dist);
        atomicAdd(&sum_score[b * T_ + t], sc);
    }
}

// --------------------------------------------------------------- final out
__global__ void combine_k(const float* __restrict__ sd, const float* __restrict__ ss,
                          float* __restrict__ out) {
    int i = blockIdx.x * 256 + threadIdx.x;
    if (i < 16 * T_) out[i] = (sd[i] * 0.1f) * (ss[i] * 0.1f);
}

// ===========================================================================
extern "C" void kernel_launch(void* const* d_in, const int* in_sizes, int n_in,
                              void* d_out, int out_size, void* d_ws, size_t ws_size,
                              hipStream_t stream) {
    const float* x     = (const float*)d_in[0];
    const float* W_emb = (const float*)d_in[1];
    const float* b_emb = (const float*)d_in[2];
    const float* ln1_g = (const float*)d_in[3];
    const float* ln1_b = (const float*)d_in[4];
    const float* W_qkv = (const float*)d_in[5];
    const float* W_o   = (const float*)d_in[6];
    const float* b_o   = (const float*)d_in[7];
    const float* ln2_g = (const float*)d_in[8];
    const float* ln2_b = (const float*)d_in[9];
    const float* W_f1  = (const float*)d_in[10];
    const float* b_f1  = (const float*)d_in[11];
    const float* W_f2  = (const float*)d_in[12];
    const float* b_f2  = (const float*)d_in[13];
    const float* c1_W  = (const float*)d_in[14];
    const float* c1_b  = (const float*)d_in[15];
    const float* bn1_g = (const float*)d_in[16];
    const float* bn1_b = (const float*)d_in[17];
    const float* bn1_m = (const float*)d_in[18];
    const float* bn1_v = (const float*)d_in[19];
    const float* c2_W  = (const float*)d_in[20];
    const float* c2_b  = (const float*)d_in[21];
    const float* bn2_g = (const float*)d_in[22];
    const float* bn2_b = (const float*)d_in[23];
    const float* bn2_m = (const float*)d_in[24];
    const float* bn2_v = (const float*)d_in[25];
    const float* c3_W  = (const float*)d_in[26];
    const float* c3_b  = (const float*)d_in[27];
    float* out = (float*)d_out;

    // ---- workspace layout (floats) — total ≈ 40 MB, chunked over bn ----
    float* ws = (float*)d_ws;
    float* Wt        = ws;                         // 3072*512   = 1,572,864
    float* s256      = Wt + (size_t)3072 * C_;     // 256
    float* sum_dist  = s256 + 256;                 // 4096
    float* sum_score = sum_dist + 4096;            // 4096
    float* h    = sum_score + 4096;                // MR*512  = 1,048,576
    float* z    = h    + (size_t)MR * C_;          // MR*512  = 1,048,576
    float* qkvt = z    + (size_t)MR * C_;          // MR*2048 = 4,194,304
    float* o    = qkvt + (size_t)MR * 4 * C_;      // MR*1024 = 2,097,152
    float* g    = o;                               // gelu buf reuses o (MR*512 fits)

    zero_k<<<(8192 + 255) / 256, 256, 0, stream>>>(sum_dist, 8192);
    wemb_transpose_k<<<(3072 * C_ + 255) / 256, 256, 0, stream>>>(W_emb, Wt);
    a2_colsum_k<<<1, 256, 0, stream>>>(s256);

    for (int cs = 0; cs < BNB; cs += CHUNK) {
        const float* xc = x + (size_t)cs * T_ * D_;

        conv_emb_k<<<dim3(C_ / 64, T_ / 64, CHUNK), 256, 0, stream>>>(xc, Wt, b_emb, h);

        for (int l = 0; l < 2; l++) {
            ln_k<<<MR, 256, 0, stream>>>(h, ln1_g + l * C_, ln1_b + l * C_, z);
            sgemm_k<<<dim3(2048 / 64, MR / 64), 256, 0, stream>>>(
                z, W_qkv + (size_t)l * C_ * 2048, nullptr, nullptr, qkvt,
                MR, 2048, C_, 0);
            attn_k<<<dim3(T_, H_, CHUNK), 256, 0, stream>>>(qkvt, s256, o);
            sgemm_k<<<dim3(C_ / 64, MR / 64), 256, 0, stream>>>(
                o, W_o + (size_t)l * 1024 * C_, b_o + l * C_, h, h,
                MR, C_, 1024, 0);
            ln_k<<<MR, 256, 0, stream>>>(h, ln2_g + l * C_, ln2_b + l * C_, z);
            sgemm_k<<<dim3(C_ / 64, MR / 64), 256, 0, stream>>>(
                z, W_f1 + (size_t)l * C_ * C_, b_f1 + l * C_, nullptr, g,
                MR, C_, C_, 1);
            sgemm_k<<<dim3(C_ / 64, MR / 64), 256, 0, stream>>>(
                g, W_f2 + (size_t)l * C_ * C_, b_f2 + l * C_, h, h,
                MR, C_, C_, 0);
        }

        head_k<<<dim3(T_, CHUNK), 64, 0, stream>>>(
            h, cs, c1_W, c1_b, bn1_g, bn1_b, bn1_m, bn1_v,
            c2_W, c2_b, bn2_g, bn2_b, bn2_m, bn2_v, c3_W, c3_b,
            sum_dist, sum_score);
    }

    combine_k<<<16, 256, 0, stream>>>(sum_dist, sum_score, out);
}

// Round 3
// 7290.154 us; speedup vs baseline: 3.5797x; 3.5797x over previous
//
#include <hip/hip_runtime.h>
#include <math.h>

#define T_    256
#define D_    1024
#define C_    512
#define H_    4
#define DH_   128
#define BNB   160
#define LEPS  1e-5f
#define INV_E 0.36787944117144233f
#define SCALE_ 0.08838834764831845f   // 1/sqrt(128)
#define LDT   40                      // LDS row stride (elems): 80 B, 16B-aligned, conflict-friendly

typedef unsigned short ushort;
typedef unsigned int   uint;
typedef __attribute__((ext_vector_type(8))) short short8;   // 8 bf16 (4 VGPRs)
typedef __attribute__((ext_vector_type(4))) float f32x4;

__device__ __forceinline__ ushort f2b(float f) {            // fp32 -> bf16 RNE
    uint u = __float_as_uint(f);
    u += 0x7fffu + ((u >> 16) & 1u);
    return (ushort)(u >> 16);
}
__device__ __forceinline__ float b2f(ushort u) {
    return __uint_as_float(((uint)u) << 16);
}
__device__ __forceinline__ uint pk(float a, float b) {
    return (uint)f2b(a) | ((uint)f2b(b) << 16);
}

// ---------------------------------------------------------------- zero fill
__global__ void zero_k(float* __restrict__ p, int n) {
    int i = blockIdx.x * 256 + threadIdx.x;
    if (i < n) p[i] = 0.0f;
}

// ---------------- generic transpose+convert: src (K,N) fp32 -> dst (N,K) bf16
__global__ void tconv_k(const float* __restrict__ src, ushort* __restrict__ dst,
                        int K, int N) {
    int idx = blockIdx.x * 256 + threadIdx.x;
    if (idx >= N * K) return;
    int n = idx / K, k = idx % K;
    dst[idx] = f2b(src[(size_t)k * N + n]);
}

// -------- W_emb (C,1024,3) -> bf16 [C][3072] with k = dt*1024+ci ordering
__global__ void wemb_k(const float* __restrict__ W, ushort* __restrict__ Wt) {
    int idx = blockIdx.x * 256 + threadIdx.x;
    if (idx >= C_ * 3072) return;
    int c = idx / 3072, k = idx % 3072;
    int dt = k >> 10, ci = k & 1023;
    Wt[idx] = f2b(W[(size_t)c * 3072 + ci * 3 + dt]);
}

// -------------------------------- s[j] = sum_k exp(-|j-k|/e)  (a2 col sums)
__global__ void a2_colsum_k(float* __restrict__ s) {
    int j = threadIdx.x;
    float acc = 0.0f;
    for (int k = 0; k < T_; k++) acc += expf(-fabsf((float)(j - k)) * INV_E);
    s[j] = acc;
}

// ------------------------------------------- LayerNorm, fp32 in -> bf16 out
__global__ __launch_bounds__(256)
void ln_k(const float* __restrict__ X, const float* __restrict__ g,
          const float* __restrict__ b, ushort* __restrict__ Z) {
    int row = blockIdx.x;
    int tid = threadIdx.x;
    const float* xr = X + (size_t)row * C_;
    float x0 = xr[tid], x1 = xr[tid + 256];
    __shared__ float red[256];
    red[tid] = x0 + x1;
    __syncthreads();
    for (int s = 128; s >= 1; s >>= 1) {
        if (tid < s) red[tid] += red[tid + s];
        __syncthreads();
    }
    float mean = red[0] * (1.0f / C_);
    __syncthreads();
    float d0 = x0 - mean, d1 = x1 - mean;
    red[tid] = d0 * d0 + d1 * d1;
    __syncthreads();
    for (int s = 128; s >= 1; s >>= 1) {
        if (tid < s) red[tid] += red[tid + s];
        __syncthreads();
    }
    float rinv = rsqrtf(red[0] * (1.0f / C_) + LEPS);
    ushort* zr = Z + (size_t)row * C_;
    zr[tid]       = f2b(d0 * rinv * g[tid]       + b[tid]);
    zr[tid + 256] = f2b(d1 * rinv * g[tid + 256] + b[tid + 256]);
}

// ======================= bf16 MFMA GEMM, 128x128 tile, BK=32 ================
// C(MxN) = A(MxK,bf16) @ B'(NxK,bf16)  [+bias] [ACT 1=gelu 2=relu] [+R fp32]
// CONV=1: A implicit im2row of Xf (fp32, chunk-local, rows=bn*256+t, k=dt*1024+ci)
template<int CONV, int ACT, int RESID, int OUTBF>
__global__ __launch_bounds__(256)
void gemm_k(const ushort* __restrict__ A, const ushort* __restrict__ B,
            const float* __restrict__ bias, const float* __restrict__ R,
            void* __restrict__ Cout, int M, int N, int K,
            const float* __restrict__ Xf) {
    __shared__ __align__(16) ushort As[128 * LDT];
    __shared__ __align__(16) ushort Bs[128 * LDT];
    const int tid  = threadIdx.x;
    const int lane = tid & 63, wave = tid >> 6;
    const int wr = wave >> 1, wc = wave & 1;
    const int lm = lane & 15, quad = lane >> 4;
    const int m0 = blockIdx.y * 128, n0 = blockIdx.x * 128;
    const int r  = tid >> 1;            // staging row 0..127
    const int c0 = (tid & 1) * 2;       // 16B-chunk pair base (0 or 2)

    f32x4 acc[4][4];
#pragma unroll
    for (int mt = 0; mt < 4; mt++)
#pragma unroll
        for (int nt = 0; nt < 4; nt++) acc[mt][nt] = (f32x4){0.f, 0.f, 0.f, 0.f};

    for (int k0 = 0; k0 < K; k0 += 32) {
        // ---- stage A tile (128 x 32) ----
        if (CONV) {
            int g = m0 + r, bn = g >> 8, t = g & 255;
#pragma unroll
            for (int cc = 0; cc < 2; cc++) {
                int c = c0 + cc;
                int kc = k0 + c * 8;
                int dt = kc >> 10, ci = kc & 1023;
                int tt = t + dt - 1;
                uint4 val;
                if (tt >= 0 && tt < T_) {
                    const float* s = Xf + (size_t)(bn * T_ + tt) * D_ + ci;
                    float4 f0 = *(const float4*)s;
                    float4 f1 = *(const float4*)(s + 4);
                    val.x = pk(f0.x, f0.y); val.y = pk(f0.z, f0.w);
                    val.z = pk(f1.x, f1.y); val.w = pk(f1.z, f1.w);
                } else {
                    val.x = 0u; val.y = 0u; val.z = 0u; val.w = 0u;
                }
                *(uint4*)&As[r * LDT + c * 8] = val;
            }
        } else {
            const ushort* Arow = A + (size_t)(m0 + r) * K + k0;
            *(uint4*)&As[r * LDT + c0 * 8]       = *(const uint4*)(Arow + c0 * 8);
            *(uint4*)&As[r * LDT + (c0 + 1) * 8] = *(const uint4*)(Arow + (c0 + 1) * 8);
        }
        // ---- stage B tile (128 x 32), B pre-transposed [N][K] ----
        {
            const ushort* Brow = B + (size_t)(n0 + r) * K + k0;
            *(uint4*)&Bs[r * LDT + c0 * 8]       = *(const uint4*)(Brow + c0 * 8);
            *(uint4*)&Bs[r * LDT + (c0 + 1) * 8] = *(const uint4*)(Brow + (c0 + 1) * 8);
        }
        __syncthreads();
        short8 af[4], bfv[4];
#pragma unroll
        for (int mt = 0; mt < 4; mt++)
            af[mt] = *(const short8*)&As[(wr * 64 + mt * 16 + lm) * LDT + quad * 8];
#pragma unroll
        for (int nt = 0; nt < 4; nt++)
            bfv[nt] = *(const short8*)&Bs[(wc * 64 + nt * 16 + lm) * LDT + quad * 8];
#pragma unroll
        for (int mt = 0; mt < 4; mt++)
#pragma unroll
            for (int nt = 0; nt < 4; nt++)
                acc[mt][nt] = __builtin_amdgcn_mfma_f32_16x16x32_bf16(
                    af[mt], bfv[nt], acc[mt][nt], 0, 0, 0);
        __syncthreads();
    }

    // ---- epilogue: D row = quad*4+reg, col = lm (m89-verified C/D layout) ----
#pragma unroll
    for (int mt = 0; mt < 4; mt++) {
        int grow0 = m0 + wr * 64 + mt * 16 + quad * 4;
#pragma unroll
        for (int nt = 0; nt < 4; nt++) {
            int gcol = n0 + wc * 64 + nt * 16 + lm;
            float bia = bias ? bias[gcol] : 0.0f;
            f32x4 v = acc[mt][nt];
#pragma unroll
            for (int i = 0; i < 4; i++) {
                int grow = grow0 + i;
                float val = v[i] + bia;
                if (ACT == 1) val = val * 0.5f * (1.0f + erff(val * 0.70710678118654752f));
                if (ACT == 2) val = fmaxf(val, 0.0f);
                if (RESID) val += R[(size_t)grow * N + gcol];
                if (OUTBF) ((ushort*)Cout)[(size_t)grow * N + gcol] = f2b(val);
                else       ((float*)Cout)[(size_t)grow * N + gcol]  = val;
            }
        }
    }
}

// ------------------------------------------------ dual attention, per query
// qkvt bf16 (MR,2048) = [q|k|v|t]; O bf16 (MR,1024)
__global__ __launch_bounds__(256)
void attn_k(const ushort* __restrict__ qkvt, const float* __restrict__ s256,
            ushort* __restrict__ O) {
    const int i  = blockIdx.x;
    const int h  = blockIdx.y;
    const int bn = blockIdx.z;
    const int tid = threadIdx.x;
    __shared__ __align__(16) float qi[DH_];
    __shared__ float p[T_];
    __shared__ float w[T_];
    __shared__ float red[256];
    const ushort* base = qkvt + (size_t)bn * T_ * 2048;
    if (tid < DH_) qi[tid] = b2f(base[(size_t)i * 2048 + h * DH_ + tid]);
    __syncthreads();
    const int j = tid;
    const uint4* k4 = (const uint4*)(base + (size_t)j * 2048 + 512 + h * DH_);
    float sc = 0.0f;
#pragma unroll
    for (int u = 0; u < 16; u++) {
        uint4 kv = k4[u];
        const float* qv = &qi[u * 8];
        sc += __uint_as_float(kv.x << 16)            * qv[0]
            + __uint_as_float(kv.x & 0xffff0000u)    * qv[1]
            + __uint_as_float(kv.y << 16)            * qv[2]
            + __uint_as_float(kv.y & 0xffff0000u)    * qv[3]
            + __uint_as_float(kv.z << 16)            * qv[4]
            + __uint_as_float(kv.z & 0xffff0000u)    * qv[5]
            + __uint_as_float(kv.w << 16)            * qv[6]
            + __uint_as_float(kv.w & 0xffff0000u)    * qv[7];
    }
    sc *= SCALE_;
    w[j] = expf(-fabsf((float)(i - j)) * INV_E) / s256[j];
    red[tid] = sc;
    __syncthreads();
    for (int s = 128; s >= 1; s >>= 1) {
        if (tid < s) red[tid] = fmaxf(red[tid], red[tid + s]);
        __syncthreads();
    }
    float mx = red[0];
    __syncthreads();
    float e = expf(sc - mx);
    red[tid] = e;
    __syncthreads();
    for (int s = 128; s >= 1; s >>= 1) {
        if (tid < s) red[tid] += red[tid + s];
        __syncthreads();
    }
    p[tid] = e / red[0];
    __syncthreads();
    float acc = 0.0f;
    if (tid < DH_) {
        const ushort* vcol = base + 1024 + h * DH_ + tid;
        for (int jj = 0; jj < T_; jj++) acc += p[jj] * b2f(vcol[(size_t)jj * 2048]);
        O[((size_t)bn * T_ + i) * 1024 + h * 256 + tid] = f2b(acc);
    } else {
        int d = tid - DH_;
        const ushort* tcol = base + 1536 + h * DH_ + d;
        for (int jj = 0; jj < T_; jj++) acc += w[jj] * b2f(tcol[(size_t)jj * 2048]);
        O[((size_t)bn * T_ + i) * 1024 + h * 256 + 128 + d] = f2b(acc);
    }
}

// --------------------------------------------------- fused head, 1 wave/(bn,t)
__global__ __launch_bounds__(64)
void head_k(const float* __restrict__ Hf, int bn_base,
            const float* __restrict__ c1W, const float* __restrict__ c1b,
            const float* __restrict__ g1, const float* __restrict__ b1,
            const float* __restrict__ m1, const float* __restrict__ v1,
            const float* __restrict__ c2W, const float* __restrict__ c2b,
            const float* __restrict__ g2, const float* __restrict__ b2,
            const float* __restrict__ m2, const float* __restrict__ v2,
            const float* __restrict__ c3W, const float* __restrict__ c3b,
            float* __restrict__ sum_dist, float* __restrict__ sum_score) {
    const int t = blockIdx.x, bn = blockIdx.y;
    const int tid = threadIdx.x;
    __shared__ float hr[C_];
    __shared__ float x1[32], y1[32], x2[16], y2[16];
    const float* row = Hf + ((size_t)bn * T_ + t) * C_;
    for (int u = tid; u < C_; u += 64) hr[u] = row[u];
    __syncthreads();
    if (tid < 32) {
        float acc = c1b[tid];
        const float* wr2 = c1W + (size_t)tid * C_;
        for (int c = 0; c < C_; c++) acc += wr2[c] * hr[c];
        x1[tid] = acc;
        y1[tid] = fmaxf(0.0f, (acc - m1[tid]) * rsqrtf(v1[tid] + LEPS) * g1[tid] + b1[tid]);
    }
    __syncthreads();
    if (tid < 16) {
        float acc = c2b[tid];
        for (int c = 0; c < 32; c++) acc += c2W[tid * 32 + c] * y1[c];
        x2[tid] = acc;
        y2[tid] = fmaxf(0.0f, (acc - m2[tid]) * rsqrtf(v2[tid] + LEPS) * g2[tid] + b2[tid]);
    }
    __syncthreads();
    if (tid == 0) {
        float d1 = 0.0f;
        for (int c = 0; c < 32; c++) { float dd = x1[c] - m1[c]; d1 += dd * dd / v1[c]; }
        float d2 = 0.0f;
        for (int c = 0; c < 16; c++) { float dd = x2[c] - m2[c]; d2 += dd * dd / v2[c]; }
        float dist = sqrtf(d1) + sqrtf(d2);
        float sc = c3b[0];
        for (int c = 0; c < 16; c++) sc += c3W[c] * y2[c];
        sc = 1.0f / (1.0f + expf(-sc));
        int b = (bn_base + bn) / 10;
        atomicAdd(&sum_dist[b * T_ + t], dist);
        atomicAdd(&sum_score[b * T_ + t], sc);
    }
}

// --------------------------------------------------------------- final out
__global__ void combine_k(const float* __restrict__ sd, const float* __restrict__ ss,
                          float* __restrict__ out) {
    int i = blockIdx.x * 256 + threadIdx.x;
    if (i < 16 * T_) out[i] = (sd[i] * 0.1f) * (ss[i] * 0.1f);
}

// ===========================================================================
extern "C" void kernel_launch(void* const* d_in, const int* in_sizes, int n_in,
                              void* d_out, int out_size, void* d_ws, size_t ws_size,
                              hipStream_t stream) {
    const float* x     = (const float*)d_in[0];
    const float* W_emb = (const float*)d_in[1];
    const float* b_emb = (const float*)d_in[2];
    const float* ln1_g = (const float*)d_in[3];
    const float* ln1_b = (const float*)d_in[4];
    const float* W_qkv = (const float*)d_in[5];
    const float* W_o   = (const float*)d_in[6];
    const float* b_o   = (const float*)d_in[7];
    const float* ln2_g = (const float*)d_in[8];
    const float* ln2_b = (const float*)d_in[9];
    const float* W_f1  = (const float*)d_in[10];
    const float* b_f1  = (const float*)d_in[11];
    const float* W_f2  = (const float*)d_in[12];
    const float* b_f2  = (const float*)d_in[13];
    const float* c1_W  = (const float*)d_in[14];
    const float* c1_b  = (const float*)d_in[15];
    const float* bn1_g = (const float*)d_in[16];
    const float* bn1_b = (const float*)d_in[17];
    const float* bn1_m = (const float*)d_in[18];
    const float* bn1_v = (const float*)d_in[19];
    const float* c2_W  = (const float*)d_in[20];
    const float* c2_b  = (const float*)d_in[21];
    const float* bn2_g = (const float*)d_in[22];
    const float* bn2_b = (const float*)d_in[23];
    const float* bn2_m = (const float*)d_in[24];
    const float* bn2_v = (const float*)d_in[25];
    const float* c3_W  = (const float*)d_in[26];
    const float* c3_b  = (const float*)d_in[27];
    float* out = (float*)d_out;

    // ---------------- workspace layout (runtime-chunked over bn) ----------
    char* p = (char*)d_ws;
    auto alloc = [&](size_t bytes) -> char* {
        char* q = p; p += (bytes + 255) & ~(size_t)255; return q;
    };
    ushort* wEmb = (ushort*)alloc((size_t)C_ * 3072 * 2);          // [512][3072]
    ushort* wQkv = (ushort*)alloc((size_t)2 * 2048 * 512 * 2);     // [l][2048][512]
    ushort* wO   = (ushort*)alloc((size_t)2 * 512 * 1024 * 2);     // [l][512][1024]
    ushort* wF1  = (ushort*)alloc((size_t)2 * 512 * 512 * 2);
    ushort* wF2  = (ushort*)alloc((size_t)2 * 512 * 512 * 2);
    float*  s256      = (float*)alloc(256 * 4);
    float*  sum_dist  = (float*)alloc(4096 * 4);
    float*  sum_score = (float*)alloc(4096 * 4);
    size_t fixedB = (size_t)(p - (char*)d_ws);

    int CH = 8;   // guaranteed-fit fallback (~31 MB total; round-1 used 39 MB OK)
    const int cands[7] = {160, 80, 40, 32, 20, 16, 10};
    for (int ci = 0; ci < 7; ci++) {
        size_t per = (size_t)cands[ci] * 256 * 9216 + 2048;
        if (fixedB + per <= ws_size) { CH = cands[ci]; break; }
    }
    const int MR = CH * 256;
    float*  h    = (float*)alloc((size_t)MR * 512 * 4);
    ushort* z    = (ushort*)alloc((size_t)MR * 512 * 2);
    ushort* qkvt = (ushort*)alloc((size_t)MR * 2048 * 2);
    ushort* o    = (ushort*)alloc((size_t)MR * 1024 * 2);  // also reused as gelu buf g
    ushort* g    = o;

    // ---------------- once-per-launch prep ----------------
    zero_k<<<(8192 + 255) / 256, 256, 0, stream>>>(sum_dist, 8192);
    a2_colsum_k<<<1, 256, 0, stream>>>(s256);
    wemb_k<<<(C_ * 3072 + 255) / 256, 256, 0, stream>>>(W_emb, wEmb);
    for (int l = 0; l < 2; l++) {
        tconv_k<<<(2048 * 512 + 255) / 256, 256, 0, stream>>>(
            W_qkv + (size_t)l * 512 * 2048, wQkv + (size_t)l * 2048 * 512, 512, 2048);
        tconv_k<<<(512 * 1024 + 255) / 256, 256, 0, stream>>>(
            W_o + (size_t)l * 1024 * 512, wO + (size_t)l * 512 * 1024, 1024, 512);
        tconv_k<<<(512 * 512 + 255) / 256, 256, 0, stream>>>(
            W_f1 + (size_t)l * 512 * 512, wF1 + (size_t)l * 512 * 512, 512, 512);
        tconv_k<<<(512 * 512 + 255) / 256, 256, 0, stream>>>(
            W_f2 + (size_t)l * 512 * 512, wF2 + (size_t)l * 512 * 512, 512, 512);
    }

    // ---------------- pipeline, chunked over bn ----------------
    for (int cs = 0; cs < BNB; cs += CH) {
        const float* xc = x + (size_t)cs * T_ * D_;

        // conv1d(k=3,pad=1)+ReLU as implicit-im2row MFMA GEMM -> h fp32
        gemm_k<1, 2, 0, 0><<<dim3(512 / 128, MR / 128), 256, 0, stream>>>(
            nullptr, wEmb, b_emb, nullptr, h, MR, 512, 3072, xc);

        for (int l = 0; l < 2; l++) {
            ln_k<<<MR, 256, 0, stream>>>(h, ln1_g + l * C_, ln1_b + l * C_, z);
            gemm_k<0, 0, 0, 1><<<dim3(2048 / 128, MR / 128), 256, 0, stream>>>(
                z, wQkv + (size_t)l * 2048 * 512, nullptr, nullptr, qkvt,
                MR, 2048, 512, nullptr);
            attn_k<<<dim3(T_, H_, CH), 256, 0, stream>>>(qkvt, s256, o);
            gemm_k<0, 0, 1, 0><<<dim3(512 / 128, MR / 128), 256, 0, stream>>>(
                o, wO + (size_t)l * 512 * 1024, b_o + l * C_, h, h,
                MR, 512, 1024, nullptr);
            ln_k<<<MR, 256, 0, stream>>>(h, ln2_g + l * C_, ln2_b + l * C_, z);
            gemm_k<0, 1, 0, 1><<<dim3(512 / 128, MR / 128), 256, 0, stream>>>(
                z, wF1 + (size_t)l * 512 * 512, b_f1 + l * C_, nullptr, g,
                MR, 512, 512, nullptr);
            gemm_k<0, 0, 1, 0><<<dim3(512 / 128, MR / 128), 256, 0, stream>>>(
                g, wF2 + (size_t)l * 512 * 512, b_f2 + l * C_, h, h,
                MR, 512, 512, nullptr);
        }

        head_k<<<dim3(T_, CH), 64, 0, stream>>>(
            h, cs, c1_W, c1_b, bn1_g, bn1_b, bn1_m, bn1_v,
            c2_W, c2_b, bn2_g, bn2_b, bn2_m, bn2_v, c3_W, c3_b,
            sum_dist, sum_score);
    }

    combine_k<<<16, 256, 0, stream>>>(sum_dist, sum_score, out);
}

// Round 4
// 2286.258 us; speedup vs baseline: 11.4147x; 3.1887x over previous
//
#include <hip/hip_runtime.h>
#include <math.h>

#define T_    256
#define D_    1024
#define C_    512
#define H_    4
#define DH_   128
#define BNB   160
#define LEPS  1e-5f
#define INV_E 0.36787944117144233f
#define SCALE_ 0.08838834764831845f   // 1/sqrt(128)
#define LDT   40                      // LDS row stride (elems) for gemm tiles

typedef unsigned short ushort;
typedef unsigned int   uint;
typedef __attribute__((ext_vector_type(8))) short short8;   // 8 bf16 (4 VGPRs)
typedef __attribute__((ext_vector_type(4))) float f32x4;

__device__ __forceinline__ ushort f2b(float f) {            // fp32 -> bf16 RNE
    uint u = __float_as_uint(f);
    u += 0x7fffu + ((u >> 16) & 1u);
    return (ushort)(u >> 16);
}
__device__ __forceinline__ float b2f(ushort u) {
    return __uint_as_float(((uint)u) << 16);
}
__device__ __forceinline__ uint pk(float a, float b) {
    return (uint)f2b(a) | ((uint)f2b(b) << 16);
}

// ---------------------------------------------------------------- zero fill
__global__ void zero_k(float* __restrict__ p, int n) {
    int i = blockIdx.x * 256 + threadIdx.x;
    if (i < n) p[i] = 0.0f;
}

// ---------------- generic transpose+convert: src (K,N) fp32 -> dst (N,K) bf16
__global__ void tconv_k(const float* __restrict__ src, ushort* __restrict__ dst,
                        int K, int N) {
    int idx = blockIdx.x * 256 + threadIdx.x;
    if (idx >= N * K) return;
    int n = idx / K, k = idx % K;
    dst[idx] = f2b(src[(size_t)k * N + n]);
}

// -------- W_emb (C,1024,3) -> bf16 [C][3072] with k = dt*1024+ci ordering
__global__ void wemb_k(const float* __restrict__ W, ushort* __restrict__ Wt) {
    int idx = blockIdx.x * 256 + threadIdx.x;
    if (idx >= C_ * 3072) return;
    int c = idx / 3072, k = idx % 3072;
    int dt = k >> 10, ci = k & 1023;
    Wt[idx] = f2b(W[(size_t)c * 3072 + ci * 3 + dt]);
}

// -------------------------------- s[j] = sum_k exp(-|j-k|/e)  (a2 col sums)
__global__ void a2_colsum_k(float* __restrict__ s) {
    int j = threadIdx.x;
    float acc = 0.0f;
    for (int k = 0; k < T_; k++) acc += expf(-fabsf((float)(j - k)) * INV_E);
    s[j] = acc;
}

// -------------------------------- A2 bf16 [i][j] = exp(-|i-j|/e)/s[j]
__global__ void a2fill_k(const float* __restrict__ s, ushort* __restrict__ A2) {
    int i = blockIdx.x, j = threadIdx.x;
    A2[i * 256 + j] = f2b(expf(-fabsf((float)(i - j)) * INV_E) / s[j]);
}

// ------------------------------------------- LayerNorm, fp32 in -> bf16 out
__global__ __launch_bounds__(256)
void ln_k(const float* __restrict__ X, const float* __restrict__ g,
          const float* __restrict__ b, ushort* __restrict__ Z) {
    int row = blockIdx.x;
    int tid = threadIdx.x;
    const float* xr = X + (size_t)row * C_;
    float x0 = xr[tid], x1 = xr[tid + 256];
    __shared__ float red[256];
    red[tid] = x0 + x1;
    __syncthreads();
    for (int s = 128; s >= 1; s >>= 1) {
        if (tid < s) red[tid] += red[tid + s];
        __syncthreads();
    }
    float mean = red[0] * (1.0f / C_);
    __syncthreads();
    float d0 = x0 - mean, d1 = x1 - mean;
    red[tid] = d0 * d0 + d1 * d1;
    __syncthreads();
    for (int s = 128; s >= 1; s >>= 1) {
        if (tid < s) red[tid] += red[tid + s];
        __syncthreads();
    }
    float rinv = rsqrtf(red[0] * (1.0f / C_) + LEPS);
    ushort* zr = Z + (size_t)row * C_;
    zr[tid]       = f2b(d0 * rinv * g[tid]       + b[tid]);
    zr[tid + 256] = f2b(d1 * rinv * g[tid + 256] + b[tid + 256]);
}

// ======================= bf16 MFMA GEMM, 128x128 tile, BK=32 ================
template<int CONV, int ACT, int RESID, int OUTBF>
__global__ __launch_bounds__(256)
void gemm_k(const ushort* __restrict__ A, const ushort* __restrict__ B,
            const float* __restrict__ bias, const float* __restrict__ R,
            void* __restrict__ Cout, int M, int N, int K,
            const float* __restrict__ Xf) {
    __shared__ __align__(16) ushort As[128 * LDT];
    __shared__ __align__(16) ushort Bs[128 * LDT];
    const int tid  = threadIdx.x;
    const int lane = tid & 63, wave = tid >> 6;
    const int wr = wave >> 1, wc = wave & 1;
    const int lm = lane & 15, quad = lane >> 4;
    const int m0 = blockIdx.y * 128, n0 = blockIdx.x * 128;
    const int r  = tid >> 1;
    const int c0 = (tid & 1) * 2;

    f32x4 acc[4][4];
#pragma unroll
    for (int mt = 0; mt < 4; mt++)
#pragma unroll
        for (int nt = 0; nt < 4; nt++) acc[mt][nt] = (f32x4){0.f, 0.f, 0.f, 0.f};

    for (int k0 = 0; k0 < K; k0 += 32) {
        if (CONV) {
            int g = m0 + r, bn = g >> 8, t = g & 255;
#pragma unroll
            for (int cc = 0; cc < 2; cc++) {
                int c = c0 + cc;
                int kc = k0 + c * 8;
                int dt = kc >> 10, ci = kc & 1023;
                int tt = t + dt - 1;
                uint4 val;
                if (tt >= 0 && tt < T_) {
                    const float* s = Xf + (size_t)(bn * T_ + tt) * D_ + ci;
                    float4 f0 = *(const float4*)s;
                    float4 f1 = *(const float4*)(s + 4);
                    val.x = pk(f0.x, f0.y); val.y = pk(f0.z, f0.w);
                    val.z = pk(f1.x, f1.y); val.w = pk(f1.z, f1.w);
                } else {
                    val.x = 0u; val.y = 0u; val.z = 0u; val.w = 0u;
                }
                *(uint4*)&As[r * LDT + c * 8] = val;
            }
        } else {
            const ushort* Arow = A + (size_t)(m0 + r) * K + k0;
            *(uint4*)&As[r * LDT + c0 * 8]       = *(const uint4*)(Arow + c0 * 8);
            *(uint4*)&As[r * LDT + (c0 + 1) * 8] = *(const uint4*)(Arow + (c0 + 1) * 8);
        }
        {
            const ushort* Brow = B + (size_t)(n0 + r) * K + k0;
            *(uint4*)&Bs[r * LDT + c0 * 8]       = *(const uint4*)(Brow + c0 * 8);
            *(uint4*)&Bs[r * LDT + (c0 + 1) * 8] = *(const uint4*)(Brow + (c0 + 1) * 8);
        }
        __syncthreads();
        short8 af[4], bfv[4];
#pragma unroll
        for (int mt = 0; mt < 4; mt++)
            af[mt] = *(const short8*)&As[(wr * 64 + mt * 16 + lm) * LDT + quad * 8];
#pragma unroll
        for (int nt = 0; nt < 4; nt++)
            bfv[nt] = *(const short8*)&Bs[(wc * 64 + nt * 16 + lm) * LDT + quad * 8];
#pragma unroll
        for (int mt = 0; mt < 4; mt++)
#pragma unroll
            for (int nt = 0; nt < 4; nt++)
                acc[mt][nt] = __builtin_amdgcn_mfma_f32_16x16x32_bf16(
                    af[mt], bfv[nt], acc[mt][nt], 0, 0, 0);
        __syncthreads();
    }

#pragma unroll
    for (int mt = 0; mt < 4; mt++) {
        int grow0 = m0 + wr * 64 + mt * 16 + quad * 4;
#pragma unroll
        for (int nt = 0; nt < 4; nt++) {
            int gcol = n0 + wc * 64 + nt * 16 + lm;
            float bia = bias ? bias[gcol] : 0.0f;
            f32x4 v = acc[mt][nt];
#pragma unroll
            for (int i = 0; i < 4; i++) {
                int grow = grow0 + i;
                float val = v[i] + bia;
                if (ACT == 1) val = val * 0.5f * (1.0f + erff(val * 0.70710678118654752f));
                if (ACT == 2) val = fmaxf(val, 0.0f);
                if (RESID) val += R[(size_t)grow * N + gcol];
                if (OUTBF) ((ushort*)Cout)[(size_t)grow * N + gcol] = f2b(val);
                else       ((float*)Cout)[(size_t)grow * N + gcol]  = val;
            }
        }
    }
}

// ================= flash-style softmax attention (o1 half), MFMA ============
// block = (bn, h); 4 waves x 64 query rows; key tiles of 32.
__global__ __launch_bounds__(256)
void attn1_k(const ushort* __restrict__ qkvt, ushort* __restrict__ O) {
    const int bn = blockIdx.x, h = blockIdx.y;
    const int tid = threadIdx.x;
    const int wave = tid >> 6, lane = tid & 63;
    const int lm = lane & 15, quad = lane >> 4;
    __shared__ __align__(16) ushort Ks[32 * 136];     // K tile: [j][d], pad 8
    __shared__ __align__(16) ushort Vt[128 * 40];     // V^T tile: [d][j], pad 8
    __shared__ __align__(16) ushort Ps[4][64 * 40];   // per-wave P: [qrow][j]
    const ushort* base = qkvt + (size_t)bn * T_ * 2048;

    // Q fragments (A-layout): row m = wave*64 + mt*16 + lm, k = ks*32+quad*8+j
    short8 aq[4][4];
#pragma unroll
    for (int mt = 0; mt < 4; mt++) {
        const ushort* qrow = base + (size_t)(wave * 64 + mt * 16 + lm) * 2048 + h * DH_;
#pragma unroll
        for (int ks = 0; ks < 4; ks++)
            aq[mt][ks] = *(const short8*)(qrow + ks * 32 + quad * 8);
    }

    f32x4 oacc[4][8];
#pragma unroll
    for (int mt = 0; mt < 4; mt++)
#pragma unroll
        for (int nt = 0; nt < 8; nt++) oacc[mt][nt] = (f32x4){0.f, 0.f, 0.f, 0.f};
    float mrow[4][4], lrow[4][4];
#pragma unroll
    for (int mt = 0; mt < 4; mt++)
#pragma unroll
        for (int i = 0; i < 4; i++) { mrow[mt][i] = -1e30f; lrow[mt][i] = 0.0f; }

    for (int kt = 0; kt < 8; kt++) {
        __syncthreads();
        // stage K tile (32 keys x 128 dims), coalesced
#pragma unroll
        for (int u = 0; u < 2; u++) {
            int ii = tid + u * 256;
            int j = ii >> 4, dc = ii & 15;
            *(uint4*)&Ks[j * 136 + dc * 8] =
                *(const uint4*)(base + (size_t)(kt * 32 + j) * 2048 + 512 + h * DH_ + dc * 8);
        }
        // stage V^T tile (transpose): thread: j = tid&31, half = tid>>5
        {
            int j = tid & 31, half = tid >> 5;
            const ushort* vrow = base + (size_t)(kt * 32 + j) * 2048 + 1024 + h * DH_ + half * 16;
            uint4 v0 = *(const uint4*)vrow;
            uint4 v1 = *(const uint4*)(vrow + 8);
            ushort e[16];
            *(uint4*)&e[0] = v0; *(uint4*)&e[8] = v1;
#pragma unroll
            for (int u = 0; u < 16; u++)
                Vt[(half * 16 + u) * 40 + j] = e[u];
        }
        __syncthreads();

        // S = Q @ K_tile^T : per wave 64 x 32
        f32x4 s[4][2];
#pragma unroll
        for (int mt = 0; mt < 4; mt++)
#pragma unroll
            for (int nt = 0; nt < 2; nt++) s[mt][nt] = (f32x4){0.f, 0.f, 0.f, 0.f};
#pragma unroll
        for (int ks = 0; ks < 4; ks++) {
            short8 bk0 = *(const short8*)&Ks[lm * 136 + ks * 32 + quad * 8];
            short8 bk1 = *(const short8*)&Ks[(16 + lm) * 136 + ks * 32 + quad * 8];
#pragma unroll
            for (int mt = 0; mt < 4; mt++) {
                s[mt][0] = __builtin_amdgcn_mfma_f32_16x16x32_bf16(aq[mt][ks], bk0, s[mt][0], 0, 0, 0);
                s[mt][1] = __builtin_amdgcn_mfma_f32_16x16x32_bf16(aq[mt][ks], bk1, s[mt][1], 0, 0, 0);
            }
        }

        // online softmax update per (mt, i): row = quad*4+i, cols = nt*16+lm
#pragma unroll
        for (int mt = 0; mt < 4; mt++) {
#pragma unroll
            for (int i = 0; i < 4; i++) {
                float v0 = s[mt][0][i] * SCALE_;
                float v1 = s[mt][1][i] * SCALE_;
                float rmax = fmaxf(v0, v1);
#pragma unroll
                for (int mk = 1; mk < 16; mk <<= 1)
                    rmax = fmaxf(rmax, __shfl_xor(rmax, mk));
                float mold = mrow[mt][i];
                float mnew = fmaxf(mold, rmax);
                float alpha = __expf(mold - mnew);
                float p0 = __expf(v0 - mnew);
                float p1 = __expf(v1 - mnew);
                float rs = p0 + p1;
#pragma unroll
                for (int mk = 1; mk < 16; mk <<= 1)
                    rs += __shfl_xor(rs, mk);
                lrow[mt][i] = lrow[mt][i] * alpha + rs;
                mrow[mt][i] = mnew;
#pragma unroll
                for (int nt = 0; nt < 8; nt++) {
                    oacc[mt][nt][i] *= alpha;
                }
                int prow = mt * 16 + quad * 4 + i;
                Ps[wave][prow * 40 + lm]      = f2b(p0);
                Ps[wave][prow * 40 + 16 + lm] = f2b(p1);
            }
        }

        // O += P @ V_tile : per wave 64 x 128, K=32 (1 k-step)
        short8 ap[4];
#pragma unroll
        for (int mt = 0; mt < 4; mt++)
            ap[mt] = *(const short8*)&Ps[wave][(mt * 16 + lm) * 40 + quad * 8];
#pragma unroll
        for (int nt = 0; nt < 8; nt++) {
            short8 bv = *(const short8*)&Vt[(nt * 16 + lm) * 40 + quad * 8];
#pragma unroll
            for (int mt = 0; mt < 4; mt++)
                oacc[mt][nt] = __builtin_amdgcn_mfma_f32_16x16x32_bf16(ap[mt], bv, oacc[mt][nt], 0, 0, 0);
        }
    }

    // epilogue: divide by l, write bf16 to O columns [h*256, h*256+128)
#pragma unroll
    for (int mt = 0; mt < 4; mt++) {
#pragma unroll
        for (int i = 0; i < 4; i++) {
            int row = wave * 64 + mt * 16 + quad * 4 + i;
            float rinv = 1.0f / lrow[mt][i];
#pragma unroll
            for (int nt = 0; nt < 8; nt++) {
                int d = nt * 16 + lm;
                O[((size_t)bn * T_ + row) * 1024 + h * 256 + d] =
                    f2b(oacc[mt][nt][i] * rinv);
            }
        }
    }
}

// ================= decay attention (o2 half): o2 = A2 @ T, batched over bn ==
// A2: [256][256] bf16 ([M][K]); T from qkvt cols 1536..2048; out cols h*256+128+d
__global__ __launch_bounds__(256)
void attn2_k(const ushort* __restrict__ A2, const ushort* __restrict__ qkvt,
             ushort* __restrict__ O) {
    __shared__ __align__(16) ushort As[128 * LDT];
    __shared__ __align__(16) ushort Bs[128 * 48];
    const int tid = threadIdx.x;
    const int bn = blockIdx.z;
    const int m0 = blockIdx.y * 128;
    const int n0 = blockIdx.x * 128;
    const int lane = tid & 63, wave = tid >> 6;
    const int wr = wave >> 1, wc = wave & 1;
    const int lm = lane & 15, quad = lane >> 4;
    const ushort* tbase = qkvt + (size_t)bn * T_ * 2048 + 1536;
    const int r = tid >> 1, c0 = (tid & 1) * 2;

    f32x4 acc[4][4];
#pragma unroll
    for (int mt = 0; mt < 4; mt++)
#pragma unroll
        for (int nt = 0; nt < 4; nt++) acc[mt][nt] = (f32x4){0.f, 0.f, 0.f, 0.f};

    for (int k0 = 0; k0 < 256; k0 += 32) {
        // A tile standard
        const ushort* Arow = A2 + (size_t)(m0 + r) * 256 + k0;
        *(uint4*)&As[r * LDT + c0 * 8]       = *(const uint4*)(Arow + c0 * 8);
        *(uint4*)&As[r * LDT + (c0 + 1) * 8] = *(const uint4*)(Arow + (c0 + 1) * 8);
        // B tile transposed on stage: Bs[n][k] = T[k0+k][n0+n]
        {
            int kr = tid & 31, np = tid >> 5;
            const ushort* trow = tbase + (size_t)(k0 + kr) * 2048 + n0 + np * 16;
            uint4 v0 = *(const uint4*)trow;
            uint4 v1 = *(const uint4*)(trow + 8);
            ushort e[16];
            *(uint4*)&e[0] = v0; *(uint4*)&e[8] = v1;
#pragma unroll
            for (int u = 0; u < 16; u++)
                Bs[(np * 16 + u) * 48 + kr] = e[u];
        }
        __syncthreads();
        short8 af[4], bf[4];
#pragma unroll
        for (int mt = 0; mt < 4; mt++)
            af[mt] = *(const short8*)&As[(wr * 64 + mt * 16 + lm) * LDT + quad * 8];
#pragma unroll
        for (int nt = 0; nt < 4; nt++)
            bf[nt] = *(const short8*)&Bs[(wc * 64 + nt * 16 + lm) * 48 + quad * 8];
#pragma unroll
        for (int mt = 0; mt < 4; mt++)
#pragma unroll
            for (int nt = 0; nt < 4; nt++)
                acc[mt][nt] = __builtin_amdgcn_mfma_f32_16x16x32_bf16(
                    af[mt], bf[nt], acc[mt][nt], 0, 0, 0);
        __syncthreads();
    }

#pragma unroll
    for (int mt = 0; mt < 4; mt++) {
        int row0 = m0 + wr * 64 + mt * 16 + quad * 4;
#pragma unroll
        for (int nt = 0; nt < 4; nt++) {
            int n = n0 + wc * 64 + nt * 16 + lm;   // 0..511 over t-cols
            int h = n >> 7, d = n & 127;
#pragma unroll
            for (int i = 0; i < 4; i++) {
                int row = row0 + i;
                O[((size_t)bn * T_ + row) * 1024 + h * 256 + 128 + d] =
                    f2b(acc[mt][nt][i]);
            }
        }
    }
}

// --------------------------------------------------- fused head, 1 wave/(bn,t)
__global__ __launch_bounds__(64)
void head_k(const float* __restrict__ Hf, int bn_base,
            const float* __restrict__ c1W, const float* __restrict__ c1b,
            const float* __restrict__ g1, const float* __restrict__ b1,
            const float* __restrict__ m1, const float* __restrict__ v1,
            const float* __restrict__ c2W, const float* __restrict__ c2b,
            const float* __restrict__ g2, const float* __restrict__ b2,
            const float* __restrict__ m2, const float* __restrict__ v2,
            const float* __restrict__ c3W, const float* __restrict__ c3b,
            float* __restrict__ sum_dist, float* __restrict__ sum_score) {
    const int t = blockIdx.x, bn = blockIdx.y;
    const int tid = threadIdx.x;
    __shared__ float hr[C_];
    __shared__ float x1[32], y1[32], x2[16], y2[16];
    const float* row = Hf + ((size_t)bn * T_ + t) * C_;
    for (int u = tid; u < C_; u += 64) hr[u] = row[u];
    __syncthreads();
    if (tid < 32) {
        float acc = c1b[tid];
        const float* wr2 = c1W + (size_t)tid * C_;
        for (int c = 0; c < C_; c++) acc += wr2[c] * hr[c];
        x1[tid] = acc;
        y1[tid] = fmaxf(0.0f, (acc - m1[tid]) * rsqrtf(v1[tid] + LEPS) * g1[tid] + b1[tid]);
    }
    __syncthreads();
    if (tid < 16) {
        float acc = c2b[tid];
        for (int c = 0; c < 32; c++) acc += c2W[tid * 32 + c] * y1[c];
        x2[tid] = acc;
        y2[tid] = fmaxf(0.0f, (acc - m2[tid]) * rsqrtf(v2[tid] + LEPS) * g2[tid] + b2[tid]);
    }
    __syncthreads();
    if (tid == 0) {
        float d1 = 0.0f;
        for (int c = 0; c < 32; c++) { float dd = x1[c] - m1[c]; d1 += dd * dd / v1[c]; }
        float d2 = 0.0f;
        for (int c = 0; c < 16; c++) { float dd = x2[c] - m2[c]; d2 += dd * dd / v2[c]; }
        float dist = sqrtf(d1) + sqrtf(d2);
        float sc = c3b[0];
        for (int c = 0; c < 16; c++) sc += c3W[c] * y2[c];
        sc = 1.0f / (1.0f + expf(-sc));
        int b = (bn_base + bn) / 10;
        atomicAdd(&sum_dist[b * T_ + t], dist);
        atomicAdd(&sum_score[b * T_ + t], sc);
    }
}

// --------------------------------------------------------------- final out
__global__ void combine_k(const float* __restrict__ sd, const float* __restrict__ ss,
                          float* __restrict__ out) {
    int i = blockIdx.x * 256 + threadIdx.x;
    if (i < 16 * T_) out[i] = (sd[i] * 0.1f) * (ss[i] * 0.1f);
}

// ===========================================================================
extern "C" void kernel_launch(void* const* d_in, const int* in_sizes, int n_in,
                              void* d_out, int out_size, void* d_ws, size_t ws_size,
                              hipStream_t stream) {
    const float* x     = (const float*)d_in[0];
    const float* W_emb = (const float*)d_in[1];
    const float* b_emb = (const float*)d_in[2];
    const float* ln1_g = (const float*)d_in[3];
    const float* ln1_b = (const float*)d_in[4];
    const float* W_qkv = (const float*)d_in[5];
    const float* W_o   = (const float*)d_in[6];
    const float* b_o   = (const float*)d_in[7];
    const float* ln2_g = (const float*)d_in[8];
    const float* ln2_b = (const float*)d_in[9];
    const float* W_f1  = (const float*)d_in[10];
    const float* b_f1  = (const float*)d_in[11];
    const float* W_f2  = (const float*)d_in[12];
    const float* b_f2  = (const float*)d_in[13];
    const float* c1_W  = (const float*)d_in[14];
    const float* c1_b  = (const float*)d_in[15];
    const float* bn1_g = (const float*)d_in[16];
    const float* bn1_b = (const float*)d_in[17];
    const float* bn1_m = (const float*)d_in[18];
    const float* bn1_v = (const float*)d_in[19];
    const float* c2_W  = (const float*)d_in[20];
    const float* c2_b  = (const float*)d_in[21];
    const float* bn2_g = (const float*)d_in[22];
    const float* bn2_b = (const float*)d_in[23];
    const float* bn2_m = (const float*)d_in[24];
    const float* bn2_v = (const float*)d_in[25];
    const float* c3_W  = (const float*)d_in[26];
    const float* c3_b  = (const float*)d_in[27];
    float* out = (float*)d_out;

    // ---------------- workspace layout (runtime-chunked over bn) ----------
    char* p = (char*)d_ws;
    auto alloc = [&](size_t bytes) -> char* {
        char* q = p; p += (bytes + 255) & ~(size_t)255; return q;
    };
    ushort* wEmb = (ushort*)alloc((size_t)C_ * 3072 * 2);
    ushort* wQkv = (ushort*)alloc((size_t)2 * 2048 * 512 * 2);
    ushort* wO   = (ushort*)alloc((size_t)2 * 512 * 1024 * 2);
    ushort* wF1  = (ushort*)alloc((size_t)2 * 512 * 512 * 2);
    ushort* wF2  = (ushort*)alloc((size_t)2 * 512 * 512 * 2);
    ushort* A2bf = (ushort*)alloc((size_t)256 * 256 * 2);
    float*  s256      = (float*)alloc(256 * 4);
    float*  sum_dist  = (float*)alloc(4096 * 4);
    float*  sum_score = (float*)alloc(4096 * 4);
    size_t fixedB = (size_t)(p - (char*)d_ws);

    int CH = 8;
    const int cands[7] = {160, 80, 40, 32, 20, 16, 10};
    for (int ci = 0; ci < 7; ci++) {
        size_t per = (size_t)cands[ci] * 256 * 9216 + 2048;
        if (fixedB + per <= ws_size) { CH = cands[ci]; break; }
    }
    const int MR = CH * 256;
    float*  h    = (float*)alloc((size_t)MR * 512 * 4);
    ushort* z    = (ushort*)alloc((size_t)MR * 512 * 2);
    ushort* qkvt = (ushort*)alloc((size_t)MR * 2048 * 2);
    ushort* o    = (ushort*)alloc((size_t)MR * 1024 * 2);
    ushort* g    = o;

    // ---------------- once-per-launch prep ----------------
    zero_k<<<(8192 + 255) / 256, 256, 0, stream>>>(sum_dist, 8192);
    a2_colsum_k<<<1, 256, 0, stream>>>(s256);
    a2fill_k<<<256, 256, 0, stream>>>(s256, A2bf);
    wemb_k<<<(C_ * 3072 + 255) / 256, 256, 0, stream>>>(W_emb, wEmb);
    for (int l = 0; l < 2; l++) {
        tconv_k<<<(2048 * 512 + 255) / 256, 256, 0, stream>>>(
            W_qkv + (size_t)l * 512 * 2048, wQkv + (size_t)l * 2048 * 512, 512, 2048);
        tconv_k<<<(512 * 1024 + 255) / 256, 256, 0, stream>>>(
            W_o + (size_t)l * 1024 * 512, wO + (size_t)l * 512 * 1024, 1024, 512);
        tconv_k<<<(512 * 512 + 255) / 256, 256, 0, stream>>>(
            W_f1 + (size_t)l * 512 * 512, wF1 + (size_t)l * 512 * 512, 512, 512);
        tconv_k<<<(512 * 512 + 255) / 256, 256, 0, stream>>>(
            W_f2 + (size_t)l * 512 * 512, wF2 + (size_t)l * 512 * 512, 512, 512);
    }

    // ---------------- pipeline, chunked over bn ----------------
    for (int cs = 0; cs < BNB; cs += CH) {
        const float* xc = x + (size_t)cs * T_ * D_;

        gemm_k<1, 2, 0, 0><<<dim3(512 / 128, MR / 128), 256, 0, stream>>>(
            nullptr, wEmb, b_emb, nullptr, h, MR, 512, 3072, xc);

        for (int l = 0; l < 2; l++) {
            ln_k<<<MR, 256, 0, stream>>>(h, ln1_g + l * C_, ln1_b + l * C_, z);
            gemm_k<0, 0, 0, 1><<<dim3(2048 / 128, MR / 128), 256, 0, stream>>>(
                z, wQkv + (size_t)l * 2048 * 512, nullptr, nullptr, qkvt,
                MR, 2048, 512, nullptr);
            attn1_k<<<dim3(CH, H_), 256, 0, stream>>>(qkvt, o);
            attn2_k<<<dim3(4, 2, CH), 256, 0, stream>>>(A2bf, qkvt, o);
            gemm_k<0, 0, 1, 0><<<dim3(512 / 128, MR / 128), 256, 0, stream>>>(
                o, wO + (size_t)l * 512 * 1024, b_o + l * C_, h, h,
                MR, 512, 1024, nullptr);
            ln_k<<<MR, 256, 0, stream>>>(h, ln2_g + l * C_, ln2_b + l * C_, z);
            gemm_k<0, 1, 0, 1><<<dim3(512 / 128, MR / 128), 256, 0, stream>>>(
                z, wF1 + (size_t)l * 512 * 512, b_f1 + l * C_, nullptr, g,
                MR, 512, 512, nullptr);
            gemm_k<0, 0, 1, 0><<<dim3(512 / 128, MR / 128), 256, 0, stream>>>(
                g, wF2 + (size_t)l * 512 * 512, b_f2 + l * C_, h, h,
                MR, 512, 512, nullptr);
        }

        head_k<<<dim3(T_, CH), 64, 0, stream>>>(
            h, cs, c1_W, c1_b, bn1_g, bn1_b, bn1_m, bn1_v,
            c2_W, c2_b, bn2_g, bn2_b, bn2_m, bn2_v, c3_W, c3_b,
            sum_dist, sum_score);
    }

    combine_k<<<16, 256, 0, stream>>>(sum_dist, sum_score, out);
}

// Round 5
// 1947.497 us; speedup vs baseline: 13.4002x; 1.1739x over previous
//
#include <hip/hip_runtime.h>
#include <math.h>

#define T_    256
#define D_    1024
#define C_    512
#define H_    4
#define DH_   128
#define BNB   160
#define LEPS  1e-5f
#define INV_E 0.36787944117144233f
#define SCALE_ 0.08838834764831845f   // 1/sqrt(128)
#define LDT   40                      // LDS row stride (elems) for gemm tiles

typedef unsigned short ushort;
typedef unsigned int   uint;
typedef __attribute__((ext_vector_type(8))) short short8;   // 8 bf16 (4 VGPRs)
typedef __attribute__((ext_vector_type(4))) float f32x4;

__device__ __forceinline__ ushort f2b(float f) {            // fp32 -> bf16 RNE
    uint u = __float_as_uint(f);
    u += 0x7fffu + ((u >> 16) & 1u);
    return (ushort)(u >> 16);
}
__device__ __forceinline__ float b2f(ushort u) {
    return __uint_as_float(((uint)u) << 16);
}
__device__ __forceinline__ uint pk(float a, float b) {
    return (uint)f2b(a) | ((uint)f2b(b) << 16);
}

// ---------------------------------------------------------------- zero fill
__global__ void zero_k(float* __restrict__ p, int n) {
    int i = blockIdx.x * 256 + threadIdx.x;
    if (i < n) p[i] = 0.0f;
}

// ---------------- generic transpose+convert: src (K,N) fp32 -> dst (N,K) bf16
__global__ void tconv_k(const float* __restrict__ src, ushort* __restrict__ dst,
                        int K, int N) {
    int idx = blockIdx.x * 256 + threadIdx.x;
    if (idx >= N * K) return;
    int n = idx / K, k = idx % K;
    dst[idx] = f2b(src[(size_t)k * N + n]);
}

// ---------------- elementwise fp32 -> bf16 convert
__global__ void bcvt_k(const float* __restrict__ src, ushort* __restrict__ dst, int n) {
    int i = blockIdx.x * 256 + threadIdx.x;
    if (i < n) dst[i] = f2b(src[i]);
}

// -------- W_emb (C,1024,3) -> bf16 [C][3072] with k = dt*1024+ci ordering
__global__ void wemb_k(const float* __restrict__ W, ushort* __restrict__ Wt) {
    int idx = blockIdx.x * 256 + threadIdx.x;
    if (idx >= C_ * 3072) return;
    int c = idx / 3072, k = idx % 3072;
    int dt = k >> 10, ci = k & 1023;
    Wt[idx] = f2b(W[(size_t)c * 3072 + ci * 3 + dt]);
}

// -------------------------------- s[j] = sum_k exp(-|j-k|/e)  (a2 col sums)
__global__ void a2_colsum_k(float* __restrict__ s) {
    int j = threadIdx.x;
    float acc = 0.0f;
    for (int k = 0; k < T_; k++) acc += expf(-fabsf((float)(j - k)) * INV_E);
    s[j] = acc;
}

// -------------------------------- A2 bf16 [i][j] = exp(-|i-j|/e)/s[j]
__global__ void a2fill_k(const float* __restrict__ s, ushort* __restrict__ A2) {
    int i = blockIdx.x, j = threadIdx.x;
    A2[i * 256 + j] = f2b(expf(-fabsf((float)(i - j)) * INV_E) / s[j]);
}

// ------------------------------------------- LayerNorm, fp32 in -> bf16 out
__global__ __launch_bounds__(256)
void ln_k(const float* __restrict__ X, const float* __restrict__ g,
          const float* __restrict__ b, ushort* __restrict__ Z) {
    int row = blockIdx.x;
    int tid = threadIdx.x;
    const float* xr = X + (size_t)row * C_;
    float x0 = xr[tid], x1 = xr[tid + 256];
    __shared__ float red[256];
    red[tid] = x0 + x1;
    __syncthreads();
    for (int s = 128; s >= 1; s >>= 1) {
        if (tid < s) red[tid] += red[tid + s];
        __syncthreads();
    }
    float mean = red[0] * (1.0f / C_);
    __syncthreads();
    float d0 = x0 - mean, d1 = x1 - mean;
    red[tid] = d0 * d0 + d1 * d1;
    __syncthreads();
    for (int s = 128; s >= 1; s >>= 1) {
        if (tid < s) red[tid] += red[tid + s];
        __syncthreads();
    }
    float rinv = rsqrtf(red[0] * (1.0f / C_) + LEPS);
    ushort* zr = Z + (size_t)row * C_;
    zr[tid]       = f2b(d0 * rinv * g[tid]       + b[tid]);
    zr[tid + 256] = f2b(d1 * rinv * g[tid + 256] + b[tid + 256]);
}

// ======================= bf16 MFMA GEMM, 128x128 tile, BK=32 ================
template<int CONV, int ACT, int RESID, int OUTBF>
__global__ __launch_bounds__(256)
void gemm_k(const ushort* __restrict__ A, const ushort* __restrict__ B,
            const float* __restrict__ bias, const float* __restrict__ R,
            void* __restrict__ Cout, int M, int N, int K,
            const float* __restrict__ Xf) {
    __shared__ __align__(16) ushort As[128 * LDT];
    __shared__ __align__(16) ushort Bs[128 * LDT];
    const int tid  = threadIdx.x;
    const int lane = tid & 63, wave = tid >> 6;
    const int wr = wave >> 1, wc = wave & 1;
    const int lm = lane & 15, quad = lane >> 4;
    const int m0 = blockIdx.y * 128, n0 = blockIdx.x * 128;
    const int r  = tid >> 1;
    const int c0 = (tid & 1) * 2;

    f32x4 acc[4][4];
#pragma unroll
    for (int mt = 0; mt < 4; mt++)
#pragma unroll
        for (int nt = 0; nt < 4; nt++) acc[mt][nt] = (f32x4){0.f, 0.f, 0.f, 0.f};

    for (int k0 = 0; k0 < K; k0 += 32) {
        if (CONV) {
            int g = m0 + r, bn = g >> 8, t = g & 255;
#pragma unroll
            for (int cc = 0; cc < 2; cc++) {
                int c = c0 + cc;
                int kc = k0 + c * 8;
                int dt = kc >> 10, ci = kc & 1023;
                int tt = t + dt - 1;
                uint4 val;
                if (tt >= 0 && tt < T_) {
                    const float* s = Xf + (size_t)(bn * T_ + tt) * D_ + ci;
                    float4 f0 = *(const float4*)s;
                    float4 f1 = *(const float4*)(s + 4);
                    val.x = pk(f0.x, f0.y); val.y = pk(f0.z, f0.w);
                    val.z = pk(f1.x, f1.y); val.w = pk(f1.z, f1.w);
                } else {
                    val.x = 0u; val.y = 0u; val.z = 0u; val.w = 0u;
                }
                *(uint4*)&As[r * LDT + c * 8] = val;
            }
        } else {
            const ushort* Arow = A + (size_t)(m0 + r) * K + k0;
            *(uint4*)&As[r * LDT + c0 * 8]       = *(const uint4*)(Arow + c0 * 8);
            *(uint4*)&As[r * LDT + (c0 + 1) * 8] = *(const uint4*)(Arow + (c0 + 1) * 8);
        }
        {
            const ushort* Brow = B + (size_t)(n0 + r) * K + k0;
            *(uint4*)&Bs[r * LDT + c0 * 8]       = *(const uint4*)(Brow + c0 * 8);
            *(uint4*)&Bs[r * LDT + (c0 + 1) * 8] = *(const uint4*)(Brow + (c0 + 1) * 8);
        }
        __syncthreads();
        short8 af[4], bfv[4];
#pragma unroll
        for (int mt = 0; mt < 4; mt++)
            af[mt] = *(const short8*)&As[(wr * 64 + mt * 16 + lm) * LDT + quad * 8];
#pragma unroll
        for (int nt = 0; nt < 4; nt++)
            bfv[nt] = *(const short8*)&Bs[(wc * 64 + nt * 16 + lm) * LDT + quad * 8];
#pragma unroll
        for (int mt = 0; mt < 4; mt++)
#pragma unroll
            for (int nt = 0; nt < 4; nt++)
                acc[mt][nt] = __builtin_amdgcn_mfma_f32_16x16x32_bf16(
                    af[mt], bfv[nt], acc[mt][nt], 0, 0, 0);
        __syncthreads();
    }

#pragma unroll
    for (int mt = 0; mt < 4; mt++) {
        int grow0 = m0 + wr * 64 + mt * 16 + quad * 4;
#pragma unroll
        for (int nt = 0; nt < 4; nt++) {
            int gcol = n0 + wc * 64 + nt * 16 + lm;
            float bia = bias ? bias[gcol] : 0.0f;
            f32x4 v = acc[mt][nt];
#pragma unroll
            for (int i = 0; i < 4; i++) {
                int grow = grow0 + i;
                float val = v[i] + bia;
                if (ACT == 1) val = val * 0.5f * (1.0f + erff(val * 0.70710678118654752f));
                if (ACT == 2) val = fmaxf(val, 0.0f);
                if (RESID) val += R[(size_t)grow * N + gcol];
                if (OUTBF) ((ushort*)Cout)[(size_t)grow * N + gcol] = f2b(val);
                else       ((float*)Cout)[(size_t)grow * N + gcol]  = val;
            }
        }
    }
}

// ================= flash-style softmax attention (o1 half), MFMA ============
__global__ __launch_bounds__(256)
void attn1_k(const ushort* __restrict__ qkvt, ushort* __restrict__ O) {
    const int bn = blockIdx.x, h = blockIdx.y;
    const int tid = threadIdx.x;
    const int wave = tid >> 6, lane = tid & 63;
    const int lm = lane & 15, quad = lane >> 4;
    __shared__ __align__(16) ushort Ks[32 * 136];
    __shared__ __align__(16) ushort Vt[128 * 40];
    __shared__ __align__(16) ushort Ps[4][64 * 40];
    const ushort* base = qkvt + (size_t)bn * T_ * 2048;

    short8 aq[4][4];
#pragma unroll
    for (int mt = 0; mt < 4; mt++) {
        const ushort* qrow = base + (size_t)(wave * 64 + mt * 16 + lm) * 2048 + h * DH_;
#pragma unroll
        for (int ks = 0; ks < 4; ks++)
            aq[mt][ks] = *(const short8*)(qrow + ks * 32 + quad * 8);
    }

    f32x4 oacc[4][8];
#pragma unroll
    for (int mt = 0; mt < 4; mt++)
#pragma unroll
        for (int nt = 0; nt < 8; nt++) oacc[mt][nt] = (f32x4){0.f, 0.f, 0.f, 0.f};
    float mrow[4][4], lrow[4][4];
#pragma unroll
    for (int mt = 0; mt < 4; mt++)
#pragma unroll
        for (int i = 0; i < 4; i++) { mrow[mt][i] = -1e30f; lrow[mt][i] = 0.0f; }

    for (int kt = 0; kt < 8; kt++) {
        __syncthreads();
#pragma unroll
        for (int u = 0; u < 2; u++) {
            int ii = tid + u * 256;
            int j = ii >> 4, dc = ii & 15;
            *(uint4*)&Ks[j * 136 + dc * 8] =
                *(const uint4*)(base + (size_t)(kt * 32 + j) * 2048 + 512 + h * DH_ + dc * 8);
        }
        {
            int j = tid & 31, half = tid >> 5;
            const ushort* vrow = base + (size_t)(kt * 32 + j) * 2048 + 1024 + h * DH_ + half * 16;
            uint4 v0 = *(const uint4*)vrow;
            uint4 v1 = *(const uint4*)(vrow + 8);
            ushort e[16];
            *(uint4*)&e[0] = v0; *(uint4*)&e[8] = v1;
#pragma unroll
            for (int u = 0; u < 16; u++)
                Vt[(half * 16 + u) * 40 + j] = e[u];
        }
        __syncthreads();

        f32x4 s[4][2];
#pragma unroll
        for (int mt = 0; mt < 4; mt++)
#pragma unroll
            for (int nt = 0; nt < 2; nt++) s[mt][nt] = (f32x4){0.f, 0.f, 0.f, 0.f};
#pragma unroll
        for (int ks = 0; ks < 4; ks++) {
            short8 bk0 = *(const short8*)&Ks[lm * 136 + ks * 32 + quad * 8];
            short8 bk1 = *(const short8*)&Ks[(16 + lm) * 136 + ks * 32 + quad * 8];
#pragma unroll
            for (int mt = 0; mt < 4; mt++) {
                s[mt][0] = __builtin_amdgcn_mfma_f32_16x16x32_bf16(aq[mt][ks], bk0, s[mt][0], 0, 0, 0);
                s[mt][1] = __builtin_amdgcn_mfma_f32_16x16x32_bf16(aq[mt][ks], bk1, s[mt][1], 0, 0, 0);
            }
        }

#pragma unroll
        for (int mt = 0; mt < 4; mt++) {
#pragma unroll
            for (int i = 0; i < 4; i++) {
                float v0 = s[mt][0][i] * SCALE_;
                float v1 = s[mt][1][i] * SCALE_;
                float rmax = fmaxf(v0, v1);
#pragma unroll
                for (int mk = 1; mk < 16; mk <<= 1)
                    rmax = fmaxf(rmax, __shfl_xor(rmax, mk));
                float mold = mrow[mt][i];
                float mnew = fmaxf(mold, rmax);
                float alpha = __expf(mold - mnew);
                float p0 = __expf(v0 - mnew);
                float p1 = __expf(v1 - mnew);
                float rs = p0 + p1;
#pragma unroll
                for (int mk = 1; mk < 16; mk <<= 1)
                    rs += __shfl_xor(rs, mk);
                lrow[mt][i] = lrow[mt][i] * alpha + rs;
                mrow[mt][i] = mnew;
#pragma unroll
                for (int nt = 0; nt < 8; nt++) {
                    oacc[mt][nt][i] *= alpha;
                }
                int prow = mt * 16 + quad * 4 + i;
                Ps[wave][prow * 40 + lm]      = f2b(p0);
                Ps[wave][prow * 40 + 16 + lm] = f2b(p1);
            }
        }

        short8 ap[4];
#pragma unroll
        for (int mt = 0; mt < 4; mt++)
            ap[mt] = *(const short8*)&Ps[wave][(mt * 16 + lm) * 40 + quad * 8];
#pragma unroll
        for (int nt = 0; nt < 8; nt++) {
            short8 bv = *(const short8*)&Vt[(nt * 16 + lm) * 40 + quad * 8];
#pragma unroll
            for (int mt = 0; mt < 4; mt++)
                oacc[mt][nt] = __builtin_amdgcn_mfma_f32_16x16x32_bf16(ap[mt], bv, oacc[mt][nt], 0, 0, 0);
        }
    }

#pragma unroll
    for (int mt = 0; mt < 4; mt++) {
#pragma unroll
        for (int i = 0; i < 4; i++) {
            int row = wave * 64 + mt * 16 + quad * 4 + i;
            float rinv = 1.0f / lrow[mt][i];
#pragma unroll
            for (int nt = 0; nt < 8; nt++) {
                int d = nt * 16 + lm;
                O[((size_t)bn * T_ + row) * 1024 + h * 256 + d] =
                    f2b(oacc[mt][nt][i] * rinv);
            }
        }
    }
}

// ================= decay attention (o2 half): o2 = A2 @ T, batched over bn ==
__global__ __launch_bounds__(256)
void attn2_k(const ushort* __restrict__ A2, const ushort* __restrict__ qkvt,
             ushort* __restrict__ O) {
    __shared__ __align__(16) ushort As[128 * LDT];
    __shared__ __align__(16) ushort Bs[128 * 48];
    const int tid = threadIdx.x;
    const int bn = blockIdx.z;
    const int m0 = blockIdx.y * 128;
    const int n0 = blockIdx.x * 128;
    const int lane = tid & 63, wave = tid >> 6;
    const int wr = wave >> 1, wc = wave & 1;
    const int lm = lane & 15, quad = lane >> 4;
    const ushort* tbase = qkvt + (size_t)bn * T_ * 2048 + 1536;
    const int r = tid >> 1, c0 = (tid & 1) * 2;

    f32x4 acc[4][4];
#pragma unroll
    for (int mt = 0; mt < 4; mt++)
#pragma unroll
        for (int nt = 0; nt < 4; nt++) acc[mt][nt] = (f32x4){0.f, 0.f, 0.f, 0.f};

    for (int k0 = 0; k0 < 256; k0 += 32) {
        const ushort* Arow = A2 + (size_t)(m0 + r) * 256 + k0;
        *(uint4*)&As[r * LDT + c0 * 8]       = *(const uint4*)(Arow + c0 * 8);
        *(uint4*)&As[r * LDT + (c0 + 1) * 8] = *(const uint4*)(Arow + (c0 + 1) * 8);
        {
            int kr = tid & 31, np = tid >> 5;
            const ushort* trow = tbase + (size_t)(k0 + kr) * 2048 + n0 + np * 16;
            uint4 v0 = *(const uint4*)trow;
            uint4 v1 = *(const uint4*)(trow + 8);
            ushort e[16];
            *(uint4*)&e[0] = v0; *(uint4*)&e[8] = v1;
#pragma unroll
            for (int u = 0; u < 16; u++)
                Bs[(np * 16 + u) * 48 + kr] = e[u];
        }
        __syncthreads();
        short8 af[4], bf[4];
#pragma unroll
        for (int mt = 0; mt < 4; mt++)
            af[mt] = *(const short8*)&As[(wr * 64 + mt * 16 + lm) * LDT + quad * 8];
#pragma unroll
        for (int nt = 0; nt < 4; nt++)
            bf[nt] = *(const short8*)&Bs[(wc * 64 + nt * 16 + lm) * 48 + quad * 8];
#pragma unroll
        for (int mt = 0; mt < 4; mt++)
#pragma unroll
            for (int nt = 0; nt < 4; nt++)
                acc[mt][nt] = __builtin_amdgcn_mfma_f32_16x16x32_bf16(
                    af[mt], bf[nt], acc[mt][nt], 0, 0, 0);
        __syncthreads();
    }

#pragma unroll
    for (int mt = 0; mt < 4; mt++) {
        int row0 = m0 + wr * 64 + mt * 16 + quad * 4;
#pragma unroll
        for (int nt = 0; nt < 4; nt++) {
            int n = n0 + wc * 64 + nt * 16 + lm;
            int h = n >> 7, d = n & 127;
#pragma unroll
            for (int i = 0; i < 4; i++) {
                int row = row0 + i;
                O[((size_t)bn * T_ + row) * 1024 + h * 256 + 128 + d] =
                    f2b(acc[mt][nt][i]);
            }
        }
    }
}

// ============ head stage 1: x1 = h @ c1W^T + c1b  (M x 32, K=512, MFMA) =====
// c1Wb: bf16 [32][512]; 128 rows per block, 4 waves x 32 rows.
#define BLD 520   // Bs ushort stride (260 dwords; 260%32=4 -> 2-way free)
__global__ __launch_bounds__(256)
void head1_k(const float* __restrict__ Hf, const ushort* __restrict__ c1Wb,
             const float* __restrict__ c1b, float* __restrict__ X1) {
    __shared__ __align__(16) ushort As[128 * LDT];
    __shared__ __align__(16) ushort Bs[32 * BLD];
    const int tid = threadIdx.x;
    const int lane = tid & 63, wave = tid >> 6;
    const int lm = lane & 15, quad = lane >> 4;
    const int m0 = blockIdx.x * 128;
    // stage full c1W (32x512 bf16) once
#pragma unroll
    for (int u = 0; u < 8; u++) {
        int ii = tid + u * 256;           // uint4 index 0..2047
        int nrow = ii >> 6;               // 64 uint4 per row
        int koff = (ii & 63) * 8;
        *(uint4*)&Bs[nrow * BLD + koff] = *(const uint4*)(c1Wb + nrow * 512 + koff);
    }
    f32x4 acc[2][2];
#pragma unroll
    for (int mt = 0; mt < 2; mt++)
#pragma unroll
        for (int nt = 0; nt < 2; nt++) acc[mt][nt] = (f32x4){0.f, 0.f, 0.f, 0.f};

    const int r = tid >> 1, half = tid & 1;
    for (int k0 = 0; k0 < 512; k0 += 32) {
        // stage A: 128 rows x 32 k, fp32 -> bf16
        const float* s = Hf + (size_t)(m0 + r) * 512 + k0 + half * 16;
        float4 f0 = *(const float4*)s;
        float4 f1 = *(const float4*)(s + 4);
        float4 f2 = *(const float4*)(s + 8);
        float4 f3 = *(const float4*)(s + 12);
        uint4 v0, v1;
        v0.x = pk(f0.x, f0.y); v0.y = pk(f0.z, f0.w);
        v0.z = pk(f1.x, f1.y); v0.w = pk(f1.z, f1.w);
        v1.x = pk(f2.x, f2.y); v1.y = pk(f2.z, f2.w);
        v1.z = pk(f3.x, f3.y); v1.w = pk(f3.z, f3.w);
        __syncthreads();
        *(uint4*)&As[r * LDT + half * 16]     = v0;
        *(uint4*)&As[r * LDT + half * 16 + 8] = v1;
        __syncthreads();
        short8 af[2], bf[2];
#pragma unroll
        for (int mt = 0; mt < 2; mt++)
            af[mt] = *(const short8*)&As[(wave * 32 + mt * 16 + lm) * LDT + quad * 8];
#pragma unroll
        for (int nt = 0; nt < 2; nt++)
            bf[nt] = *(const short8*)&Bs[(nt * 16 + lm) * BLD + k0 + quad * 8];
#pragma unroll
        for (int mt = 0; mt < 2; mt++)
#pragma unroll
            for (int nt = 0; nt < 2; nt++)
                acc[mt][nt] = __builtin_amdgcn_mfma_f32_16x16x32_bf16(
                    af[mt], bf[nt], acc[mt][nt], 0, 0, 0);
    }
#pragma unroll
    for (int mt = 0; mt < 2; mt++) {
        int row0 = m0 + wave * 32 + mt * 16 + quad * 4;
#pragma unroll
        for (int nt = 0; nt < 2; nt++) {
            int col = nt * 16 + lm;
            float bia = c1b[col];
#pragma unroll
            for (int i = 0; i < 4; i++)
                X1[(size_t)(row0 + i) * 32 + col] = acc[mt][nt][i] + bia;
        }
    }
}

// ============ head stage 2: one thread per (bn,t) row ========================
__global__ __launch_bounds__(256)
void head2_k(const float* __restrict__ X1, int bn_base, int M,
             const float* __restrict__ g1, const float* __restrict__ b1,
             const float* __restrict__ m1, const float* __restrict__ v1,
             const float* __restrict__ c2W, const float* __restrict__ c2b,
             const float* __restrict__ g2, const float* __restrict__ b2,
             const float* __restrict__ m2, const float* __restrict__ v2,
             const float* __restrict__ c3W, const float* __restrict__ c3b,
             float* __restrict__ sum_dist, float* __restrict__ sum_score) {
    int row = blockIdx.x * 256 + threadIdx.x;
    if (row >= M) return;
    float x1[32], y1[32];
    const float* xr = X1 + (size_t)row * 32;
#pragma unroll
    for (int c = 0; c < 32; c++) x1[c] = xr[c];
    float d1 = 0.0f;
#pragma unroll
    for (int c = 0; c < 32; c++) {
        float dd = x1[c] - m1[c];
        d1 += dd * dd / v1[c];
        y1[c] = fmaxf(0.0f, dd * rsqrtf(v1[c] + LEPS) * g1[c] + b1[c]);
    }
    float d2 = 0.0f, sc = c3b[0];
#pragma unroll
    for (int o = 0; o < 16; o++) {
        float acc = c2b[o];
        const float* wr = c2W + o * 32;
#pragma unroll
        for (int c = 0; c < 32; c++) acc += wr[c] * y1[c];
        float dd = acc - m2[o];
        d2 += dd * dd / v2[o];
        float y2 = fmaxf(0.0f, dd * rsqrtf(v2[o] + LEPS) * g2[o] + b2[o]);
        sc += c3W[o] * y2;
    }
    float dist = sqrtf(d1) + sqrtf(d2);
    sc = 1.0f / (1.0f + expf(-sc));
    int bn = bn_base + (row >> 8);
    int t = row & 255;
    int b = bn / 10;
    atomicAdd(&sum_dist[b * T_ + t], dist);
    atomicAdd(&sum_score[b * T_ + t], sc);
}

// --------------------------------------------------------------- final out
__global__ void combine_k(const float* __restrict__ sd, const float* __restrict__ ss,
                          float* __restrict__ out) {
    int i = blockIdx.x * 256 + threadIdx.x;
    if (i < 16 * T_) out[i] = (sd[i] * 0.1f) * (ss[i] * 0.1f);
}

// ===========================================================================
extern "C" void kernel_launch(void* const* d_in, const int* in_sizes, int n_in,
                              void* d_out, int out_size, void* d_ws, size_t ws_size,
                              hipStream_t stream) {
    const float* x     = (const float*)d_in[0];
    const float* W_emb = (const float*)d_in[1];
    const float* b_emb = (const float*)d_in[2];
    const float* ln1_g = (const float*)d_in[3];
    const float* ln1_b = (const float*)d_in[4];
    const float* W_qkv = (const float*)d_in[5];
    const float* W_o   = (const float*)d_in[6];
    const float* b_o   = (const float*)d_in[7];
    const float* ln2_g = (const float*)d_in[8];
    const float* ln2_b = (const float*)d_in[9];
    const float* W_f1  = (const float*)d_in[10];
    const float* b_f1  = (const float*)d_in[11];
    const float* W_f2  = (const float*)d_in[12];
    const float* b_f2  = (const float*)d_in[13];
    const float* c1_W  = (const float*)d_in[14];
    const float* c1_b  = (const float*)d_in[15];
    const float* bn1_g = (const float*)d_in[16];
    const float* bn1_b = (const float*)d_in[17];
    const float* bn1_m = (const float*)d_in[18];
    const float* bn1_v = (const float*)d_in[19];
    const float* c2_W  = (const float*)d_in[20];
    const float* c2_b  = (const float*)d_in[21];
    const float* bn2_g = (const float*)d_in[22];
    const float* bn2_b = (const float*)d_in[23];
    const float* bn2_m = (const float*)d_in[24];
    const float* bn2_v = (const float*)d_in[25];
    const float* c3_W  = (const float*)d_in[26];
    const float* c3_b  = (const float*)d_in[27];
    float* out = (float*)d_out;

    // ---------------- workspace layout (runtime-chunked over bn) ----------
    char* p = (char*)d_ws;
    auto alloc = [&](size_t bytes) -> char* {
        char* q = p; p += (bytes + 255) & ~(size_t)255; return q;
    };
    ushort* wEmb = (ushort*)alloc((size_t)C_ * 3072 * 2);
    ushort* wQkv = (ushort*)alloc((size_t)2 * 2048 * 512 * 2);
    ushort* wO   = (ushort*)alloc((size_t)2 * 512 * 1024 * 2);
    ushort* wF1  = (ushort*)alloc((size_t)2 * 512 * 512 * 2);
    ushort* wF2  = (ushort*)alloc((size_t)2 * 512 * 512 * 2);
    ushort* A2bf = (ushort*)alloc((size_t)256 * 256 * 2);
    ushort* c1Wb = (ushort*)alloc((size_t)32 * 512 * 2);
    float*  s256      = (float*)alloc(256 * 4);
    float*  sum_dist  = (float*)alloc(4096 * 4);
    float*  sum_score = (float*)alloc(4096 * 4);
    size_t fixedB = (size_t)(p - (char*)d_ws);

    int CH = 8;
    const int cands[7] = {160, 80, 40, 32, 20, 16, 10};
    for (int ci = 0; ci < 7; ci++) {
        size_t per = (size_t)cands[ci] * 256 * 9344 + 4096;
        if (fixedB + per <= ws_size) { CH = cands[ci]; break; }
    }
    const int MR = CH * 256;
    float*  h    = (float*)alloc((size_t)MR * 512 * 4);
    ushort* z    = (ushort*)alloc((size_t)MR * 512 * 2);
    ushort* qkvt = (ushort*)alloc((size_t)MR * 2048 * 2);
    ushort* o    = (ushort*)alloc((size_t)MR * 1024 * 2);
    ushort* g    = o;
    float*  X1   = (float*)alloc((size_t)MR * 32 * 4);

    // ---------------- once-per-launch prep ----------------
    zero_k<<<(8192 + 255) / 256, 256, 0, stream>>>(sum_dist, 8192);
    a2_colsum_k<<<1, 256, 0, stream>>>(s256);
    a2fill_k<<<256, 256, 0, stream>>>(s256, A2bf);
    wemb_k<<<(C_ * 3072 + 255) / 256, 256, 0, stream>>>(W_emb, wEmb);
    bcvt_k<<<(32 * 512 + 255) / 256, 256, 0, stream>>>(c1_W, c1Wb, 32 * 512);
    for (int l = 0; l < 2; l++) {
        tconv_k<<<(2048 * 512 + 255) / 256, 256, 0, stream>>>(
            W_qkv + (size_t)l * 512 * 2048, wQkv + (size_t)l * 2048 * 512, 512, 2048);
        tconv_k<<<(512 * 1024 + 255) / 256, 256, 0, stream>>>(
            W_o + (size_t)l * 1024 * 512, wO + (size_t)l * 512 * 1024, 1024, 512);
        tconv_k<<<(512 * 512 + 255) / 256, 256, 0, stream>>>(
            W_f1 + (size_t)l * 512 * 512, wF1 + (size_t)l * 512 * 512, 512, 512);
        tconv_k<<<(512 * 512 + 255) / 256, 256, 0, stream>>>(
            W_f2 + (size_t)l * 512 * 512, wF2 + (size_t)l * 512 * 512, 512, 512);
    }

    // ---------------- pipeline, chunked over bn ----------------
    for (int cs = 0; cs < BNB; cs += CH) {
        const float* xc = x + (size_t)cs * T_ * D_;

        gemm_k<1, 2, 0, 0><<<dim3(512 / 128, MR / 128), 256, 0, stream>>>(
            nullptr, wEmb, b_emb, nullptr, h, MR, 512, 3072, xc);

        for (int l = 0; l < 2; l++) {
            ln_k<<<MR, 256, 0, stream>>>(h, ln1_g + l * C_, ln1_b + l * C_, z);
            gemm_k<0, 0, 0, 1><<<dim3(2048 / 128, MR / 128), 256, 0, stream>>>(
                z, wQkv + (size_t)l * 2048 * 512, nullptr, nullptr, qkvt,
                MR, 2048, 512, nullptr);
            attn1_k<<<dim3(CH, H_), 256, 0, stream>>>(qkvt, o);
            attn2_k<<<dim3(4, 2, CH), 256, 0, stream>>>(A2bf, qkvt, o);
            gemm_k<0, 0, 1, 0><<<dim3(512 / 128, MR / 128), 256, 0, stream>>>(
                o, wO + (size_t)l * 512 * 1024, b_o + l * C_, h, h,
                MR, 512, 1024, nullptr);
            ln_k<<<MR, 256, 0, stream>>>(h, ln2_g + l * C_, ln2_b + l * C_, z);
            gemm_k<0, 1, 0, 1><<<dim3(512 / 128, MR / 128), 256, 0, stream>>>(
                z, wF1 + (size_t)l * 512 * 512, b_f1 + l * C_, nullptr, g,
                MR, 512, 512, nullptr);
            gemm_k<0, 0, 1, 0><<<dim3(512 / 128, MR / 128), 256, 0, stream>>>(
                g, wF2 + (size_t)l * 512 * 512, b_f2 + l * C_, h, h,
                MR, 512, 512, nullptr);
        }

        head1_k<<<MR / 128, 256, 0, stream>>>(h, c1Wb, c1_b, X1);
        head2_k<<<MR / 256, 256, 0, stream>>>(
            X1, cs, MR, bn1_g, bn1_b, bn1_m, bn1_v,
            c2_W, c2_b, bn2_g, bn2_b, bn2_m, bn2_v, c3_W, c3_b,
            sum_dist, sum_score);
    }

    combine_k<<<16, 256, 0, stream>>>(sum_dist, sum_score, out);
}

// Round 6
// 1840.749 us; speedup vs baseline: 14.1773x; 1.0580x over previous
//
#include <hip/hip_runtime.h>
#include <math.h>

#define T_    256
#define D_    1024
#define C_    512
#define H_    4
#define DH_   128
#define BNB   160
#define LEPS  1e-5f
#define INV_E 0.36787944117144233f
#define SCALE_ 0.08838834764831845f   // 1/sqrt(128)
#define LDT   40                      // LDS row stride (elems) for gemm tiles

typedef unsigned short ushort;
typedef unsigned int   uint;
typedef __attribute__((ext_vector_type(8))) short short8;   // 8 bf16 (4 VGPRs)
typedef __attribute__((ext_vector_type(4))) float f32x4;

__device__ __forceinline__ ushort f2b(float f) {            // fp32 -> bf16 RNE
    uint u = __float_as_uint(f);
    u += 0x7fffu + ((u >> 16) & 1u);
    return (ushort)(u >> 16);
}
__device__ __forceinline__ float b2f(ushort u) {
    return __uint_as_float(((uint)u) << 16);
}
__device__ __forceinline__ uint pk(float a, float b) {
    return (uint)f2b(a) | ((uint)f2b(b) << 16);
}

// ---------------------------------------------------------------- zero fill
__global__ void zero_k(float* __restrict__ p, int n) {
    int i = blockIdx.x * 256 + threadIdx.x;
    if (i < n) p[i] = 0.0f;
}

// ---------------- x fp32 -> bf16, 4 elems/thread
__global__ void xcvt_k(const float* __restrict__ src, ushort* __restrict__ dst, int n4) {
    int i = blockIdx.x * 256 + threadIdx.x;
    if (i < n4) {
        float4 f = ((const float4*)src)[i];
        uint2 v;
        v.x = pk(f.x, f.y);
        v.y = pk(f.z, f.w);
        ((uint2*)dst)[i] = v;
    }
}

// ---------------- generic transpose+convert: src (K,N) fp32 -> dst (N,K) bf16
__global__ void tconv_k(const float* __restrict__ src, ushort* __restrict__ dst,
                        int K, int N) {
    int idx = blockIdx.x * 256 + threadIdx.x;
    if (idx >= N * K) return;
    int n = idx / K, k = idx % K;
    dst[idx] = f2b(src[(size_t)k * N + n]);
}

// ---------------- elementwise fp32 -> bf16 convert
__global__ void bcvt_k(const float* __restrict__ src, ushort* __restrict__ dst, int n) {
    int i = blockIdx.x * 256 + threadIdx.x;
    if (i < n) dst[i] = f2b(src[i]);
}

// -------- W_emb (C,1024,3) -> bf16 [C][3072] with k = dt*1024+ci ordering
__global__ void wemb_k(const float* __restrict__ W, ushort* __restrict__ Wt) {
    int idx = blockIdx.x * 256 + threadIdx.x;
    if (idx >= C_ * 3072) return;
    int c = idx / 3072, k = idx % 3072;
    int dt = k >> 10, ci = k & 1023;
    Wt[idx] = f2b(W[(size_t)c * 3072 + ci * 3 + dt]);
}

// -------------------------------- s[j] = sum_k exp(-|j-k|/e)  (a2 col sums)
__global__ void a2_colsum_k(float* __restrict__ s) {
    int j = threadIdx.x;
    float acc = 0.0f;
    for (int k = 0; k < T_; k++) acc += expf(-fabsf((float)(j - k)) * INV_E);
    s[j] = acc;
}

// -------------------------------- A2 bf16 [i][j] = exp(-|i-j|/e)/s[j]
__global__ void a2fill_k(const float* __restrict__ s, ushort* __restrict__ A2) {
    int i = blockIdx.x, j = threadIdx.x;
    A2[i * 256 + j] = f2b(expf(-fabsf((float)(i - j)) * INV_E) / s[j]);
}

// ------------------------------------------- LayerNorm, bf16 in -> bf16 out
__global__ __launch_bounds__(256)
void ln_k(const ushort* __restrict__ X, const float* __restrict__ g,
          const float* __restrict__ b, ushort* __restrict__ Z) {
    int row = blockIdx.x;
    int tid = threadIdx.x;
    const ushort* xr = X + (size_t)row * C_;
    float x0 = b2f(xr[tid]), x1 = b2f(xr[tid + 256]);
    __shared__ float red[256];
    red[tid] = x0 + x1;
    __syncthreads();
    for (int s = 128; s >= 1; s >>= 1) {
        if (tid < s) red[tid] += red[tid + s];
        __syncthreads();
    }
    float mean = red[0] * (1.0f / C_);
    __syncthreads();
    float d0 = x0 - mean, d1 = x1 - mean;
    red[tid] = d0 * d0 + d1 * d1;
    __syncthreads();
    for (int s = 128; s >= 1; s >>= 1) {
        if (tid < s) red[tid] += red[tid + s];
        __syncthreads();
    }
    float rinv = rsqrtf(red[0] * (1.0f / C_) + LEPS);
    ushort* zr = Z + (size_t)row * C_;
    zr[tid]       = f2b(d0 * rinv * g[tid]       + b[tid]);
    zr[tid + 256] = f2b(d1 * rinv * g[tid + 256] + b[tid + 256]);
}

// ======================= bf16 MFMA GEMM, 128x128 tile, BK=32 ================
// C(MxN) = A(MxK,bf16) @ B'(NxK,bf16)  [+bias] [ACT 1=gelu 2=relu] [+R bf16]
// CONV=1: A implicit im2row of Xb (bf16, chunk-local, k = dt*1024+ci)
template<int CONV, int ACT, int RESID, int OUTBF>
__global__ __launch_bounds__(256)
void gemm_k(const ushort* __restrict__ A, const ushort* __restrict__ B,
            const float* __restrict__ bias, const ushort* __restrict__ R,
            void* __restrict__ Cout, int M, int N, int K,
            const ushort* __restrict__ Xb) {
    __shared__ __align__(16) ushort As[128 * LDT];
    __shared__ __align__(16) ushort Bs[128 * LDT];
    const int tid  = threadIdx.x;
    const int lane = tid & 63, wave = tid >> 6;
    const int wr = wave >> 1, wc = wave & 1;
    const int lm = lane & 15, quad = lane >> 4;
    const int m0 = blockIdx.y * 128, n0 = blockIdx.x * 128;
    const int r  = tid >> 1;
    const int c0 = (tid & 1) * 2;

    f32x4 acc[4][4];
#pragma unroll
    for (int mt = 0; mt < 4; mt++)
#pragma unroll
        for (int nt = 0; nt < 4; nt++) acc[mt][nt] = (f32x4){0.f, 0.f, 0.f, 0.f};

    for (int k0 = 0; k0 < K; k0 += 32) {
        if (CONV) {
            int g = m0 + r, bn = g >> 8, t = g & 255;
#pragma unroll
            for (int cc = 0; cc < 2; cc++) {
                int c = c0 + cc;
                int kc = k0 + c * 8;
                int dt = kc >> 10, ci = kc & 1023;
                int tt = t + dt - 1;
                uint4 val;
                if (tt >= 0 && tt < T_) {
                    val = *(const uint4*)(Xb + ((size_t)bn * T_ + tt) * D_ + ci);
                } else {
                    val.x = 0u; val.y = 0u; val.z = 0u; val.w = 0u;
                }
                *(uint4*)&As[r * LDT + c * 8] = val;
            }
        } else {
            const ushort* Arow = A + (size_t)(m0 + r) * K + k0;
            *(uint4*)&As[r * LDT + c0 * 8]       = *(const uint4*)(Arow + c0 * 8);
            *(uint4*)&As[r * LDT + (c0 + 1) * 8] = *(const uint4*)(Arow + (c0 + 1) * 8);
        }
        {
            const ushort* Brow = B + (size_t)(n0 + r) * K + k0;
            *(uint4*)&Bs[r * LDT + c0 * 8]       = *(const uint4*)(Brow + c0 * 8);
            *(uint4*)&Bs[r * LDT + (c0 + 1) * 8] = *(const uint4*)(Brow + (c0 + 1) * 8);
        }
        __syncthreads();
        short8 af[4], bfv[4];
#pragma unroll
        for (int mt = 0; mt < 4; mt++)
            af[mt] = *(const short8*)&As[(wr * 64 + mt * 16 + lm) * LDT + quad * 8];
#pragma unroll
        for (int nt = 0; nt < 4; nt++)
            bfv[nt] = *(const short8*)&Bs[(wc * 64 + nt * 16 + lm) * LDT + quad * 8];
#pragma unroll
        for (int mt = 0; mt < 4; mt++)
#pragma unroll
            for (int nt = 0; nt < 4; nt++)
                acc[mt][nt] = __builtin_amdgcn_mfma_f32_16x16x32_bf16(
                    af[mt], bfv[nt], acc[mt][nt], 0, 0, 0);
        __syncthreads();
    }

#pragma unroll
    for (int mt = 0; mt < 4; mt++) {
        int grow0 = m0 + wr * 64 + mt * 16 + quad * 4;
#pragma unroll
        for (int nt = 0; nt < 4; nt++) {
            int gcol = n0 + wc * 64 + nt * 16 + lm;
            float bia = bias ? bias[gcol] : 0.0f;
            f32x4 v = acc[mt][nt];
#pragma unroll
            for (int i = 0; i < 4; i++) {
                int grow = grow0 + i;
                float val = v[i] + bia;
                if (ACT == 1) val = val * 0.5f * (1.0f + erff(val * 0.70710678118654752f));
                if (ACT == 2) val = fmaxf(val, 0.0f);
                if (RESID) val += b2f(R[(size_t)grow * N + gcol]);
                if (OUTBF) ((ushort*)Cout)[(size_t)grow * N + gcol] = f2b(val);
                else       ((float*)Cout)[(size_t)grow * N + gcol]  = val;
            }
        }
    }
}

// ================= flash-style softmax attention (o1 half), MFMA ============
__global__ __launch_bounds__(256)
void attn1_k(const ushort* __restrict__ qkvt, ushort* __restrict__ O) {
    const int bn = blockIdx.x, h = blockIdx.y;
    const int tid = threadIdx.x;
    const int wave = tid >> 6, lane = tid & 63;
    const int lm = lane & 15, quad = lane >> 4;
    __shared__ __align__(16) ushort Ks[32 * 136];
    __shared__ __align__(16) ushort Vt[128 * 40];
    __shared__ __align__(16) ushort Ps[4][64 * 40];
    const ushort* base = qkvt + (size_t)bn * T_ * 2048;

    short8 aq[4][4];
#pragma unroll
    for (int mt = 0; mt < 4; mt++) {
        const ushort* qrow = base + (size_t)(wave * 64 + mt * 16 + lm) * 2048 + h * DH_;
#pragma unroll
        for (int ks = 0; ks < 4; ks++)
            aq[mt][ks] = *(const short8*)(qrow + ks * 32 + quad * 8);
    }

    f32x4 oacc[4][8];
#pragma unroll
    for (int mt = 0; mt < 4; mt++)
#pragma unroll
        for (int nt = 0; nt < 8; nt++) oacc[mt][nt] = (f32x4){0.f, 0.f, 0.f, 0.f};
    float mrow[4][4], lrow[4][4];
#pragma unroll
    for (int mt = 0; mt < 4; mt++)
#pragma unroll
        for (int i = 0; i < 4; i++) { mrow[mt][i] = -1e30f; lrow[mt][i] = 0.0f; }

    for (int kt = 0; kt < 8; kt++) {
        __syncthreads();
#pragma unroll
        for (int u = 0; u < 2; u++) {
            int ii = tid + u * 256;
            int j = ii >> 4, dc = ii & 15;
            *(uint4*)&Ks[j * 136 + dc * 8] =
                *(const uint4*)(base + (size_t)(kt * 32 + j) * 2048 + 512 + h * DH_ + dc * 8);
        }
        {
            int j = tid & 31, half = tid >> 5;
            const ushort* vrow = base + (size_t)(kt * 32 + j) * 2048 + 1024 + h * DH_ + half * 16;
            uint4 v0 = *(const uint4*)vrow;
            uint4 v1 = *(const uint4*)(vrow + 8);
            ushort e[16];
            *(uint4*)&e[0] = v0; *(uint4*)&e[8] = v1;
#pragma unroll
            for (int u = 0; u < 16; u++)
                Vt[(half * 16 + u) * 40 + j] = e[u];
        }
        __syncthreads();

        f32x4 s[4][2];
#pragma unroll
        for (int mt = 0; mt < 4; mt++)
#pragma unroll
            for (int nt = 0; nt < 2; nt++) s[mt][nt] = (f32x4){0.f, 0.f, 0.f, 0.f};
#pragma unroll
        for (int ks = 0; ks < 4; ks++) {
            short8 bk0 = *(const short8*)&Ks[lm * 136 + ks * 32 + quad * 8];
            short8 bk1 = *(const short8*)&Ks[(16 + lm) * 136 + ks * 32 + quad * 8];
#pragma unroll
            for (int mt = 0; mt < 4; mt++) {
                s[mt][0] = __builtin_amdgcn_mfma_f32_16x16x32_bf16(aq[mt][ks], bk0, s[mt][0], 0, 0, 0);
                s[mt][1] = __builtin_amdgcn_mfma_f32_16x16x32_bf16(aq[mt][ks], bk1, s[mt][1], 0, 0, 0);
            }
        }

#pragma unroll
        for (int mt = 0; mt < 4; mt++) {
#pragma unroll
            for (int i = 0; i < 4; i++) {
                float v0 = s[mt][0][i] * SCALE_;
                float v1 = s[mt][1][i] * SCALE_;
                float rmax = fmaxf(v0, v1);
#pragma unroll
                for (int mk = 1; mk < 16; mk <<= 1)
                    rmax = fmaxf(rmax, __shfl_xor(rmax, mk));
                float mold = mrow[mt][i];
                float mnew = fmaxf(mold, rmax);
                float alpha = __expf(mold - mnew);
                float p0 = __expf(v0 - mnew);
                float p1 = __expf(v1 - mnew);
                float rs = p0 + p1;
#pragma unroll
                for (int mk = 1; mk < 16; mk <<= 1)
                    rs += __shfl_xor(rs, mk);
                lrow[mt][i] = lrow[mt][i] * alpha + rs;
                mrow[mt][i] = mnew;
#pragma unroll
                for (int nt = 0; nt < 8; nt++) {
                    oacc[mt][nt][i] *= alpha;
                }
                int prow = mt * 16 + quad * 4 + i;
                Ps[wave][prow * 40 + lm]      = f2b(p0);
                Ps[wave][prow * 40 + 16 + lm] = f2b(p1);
            }
        }

        short8 ap[4];
#pragma unroll
        for (int mt = 0; mt < 4; mt++)
            ap[mt] = *(const short8*)&Ps[wave][(mt * 16 + lm) * 40 + quad * 8];
#pragma unroll
        for (int nt = 0; nt < 8; nt++) {
            short8 bv = *(const short8*)&Vt[(nt * 16 + lm) * 40 + quad * 8];
#pragma unroll
            for (int mt = 0; mt < 4; mt++)
                oacc[mt][nt] = __builtin_amdgcn_mfma_f32_16x16x32_bf16(ap[mt], bv, oacc[mt][nt], 0, 0, 0);
        }
    }

#pragma unroll
    for (int mt = 0; mt < 4; mt++) {
#pragma unroll
        for (int i = 0; i < 4; i++) {
            int row = wave * 64 + mt * 16 + quad * 4 + i;
            float rinv = 1.0f / lrow[mt][i];
#pragma unroll
            for (int nt = 0; nt < 8; nt++) {
                int d = nt * 16 + lm;
                O[((size_t)bn * T_ + row) * 1024 + h * 256 + d] =
                    f2b(oacc[mt][nt][i] * rinv);
            }
        }
    }
}

// ================= decay attention (o2 half): o2 = A2 @ T, batched over bn ==
__global__ __launch_bounds__(256)
void attn2_k(const ushort* __restrict__ A2, const ushort* __restrict__ qkvt,
             ushort* __restrict__ O) {
    __shared__ __align__(16) ushort As[128 * LDT];
    __shared__ __align__(16) ushort Bs[128 * 48];
    const int tid = threadIdx.x;
    const int bn = blockIdx.z;
    const int m0 = blockIdx.y * 128;
    const int n0 = blockIdx.x * 128;
    const int lane = tid & 63, wave = tid >> 6;
    const int wr = wave >> 1, wc = wave & 1;
    const int lm = lane & 15, quad = lane >> 4;
    const ushort* tbase = qkvt + (size_t)bn * T_ * 2048 + 1536;
    const int r = tid >> 1, c0 = (tid & 1) * 2;

    f32x4 acc[4][4];
#pragma unroll
    for (int mt = 0; mt < 4; mt++)
#pragma unroll
        for (int nt = 0; nt < 4; nt++) acc[mt][nt] = (f32x4){0.f, 0.f, 0.f, 0.f};

    for (int k0 = 0; k0 < 256; k0 += 32) {
        const ushort* Arow = A2 + (size_t)(m0 + r) * 256 + k0;
        *(uint4*)&As[r * LDT + c0 * 8]       = *(const uint4*)(Arow + c0 * 8);
        *(uint4*)&As[r * LDT + (c0 + 1) * 8] = *(const uint4*)(Arow + (c0 + 1) * 8);
        {
            int kr = tid & 31, np = tid >> 5;
            const ushort* trow = tbase + (size_t)(k0 + kr) * 2048 + n0 + np * 16;
            uint4 v0 = *(const uint4*)trow;
            uint4 v1 = *(const uint4*)(trow + 8);
            ushort e[16];
            *(uint4*)&e[0] = v0; *(uint4*)&e[8] = v1;
#pragma unroll
            for (int u = 0; u < 16; u++)
                Bs[(np * 16 + u) * 48 + kr] = e[u];
        }
        __syncthreads();
        short8 af[4], bf[4];
#pragma unroll
        for (int mt = 0; mt < 4; mt++)
            af[mt] = *(const short8*)&As[(wr * 64 + mt * 16 + lm) * LDT + quad * 8];
#pragma unroll
        for (int nt = 0; nt < 4; nt++)
            bf[nt] = *(const short8*)&Bs[(wc * 64 + nt * 16 + lm) * 48 + quad * 8];
#pragma unroll
        for (int mt = 0; mt < 4; mt++)
#pragma unroll
            for (int nt = 0; nt < 4; nt++)
                acc[mt][nt] = __builtin_amdgcn_mfma_f32_16x16x32_bf16(
                    af[mt], bf[nt], acc[mt][nt], 0, 0, 0);
        __syncthreads();
    }

#pragma unroll
    for (int mt = 0; mt < 4; mt++) {
        int row0 = m0 + wr * 64 + mt * 16 + quad * 4;
#pragma unroll
        for (int nt = 0; nt < 4; nt++) {
            int n = n0 + wc * 64 + nt * 16 + lm;
            int h = n >> 7, d = n & 127;
#pragma unroll
            for (int i = 0; i < 4; i++) {
                int row = row0 + i;
                O[((size_t)bn * T_ + row) * 1024 + h * 256 + 128 + d] =
                    f2b(acc[mt][nt][i]);
            }
        }
    }
}

// ============ head stage 1: x1 = h @ c1W^T + c1b  (M x 32, K=512, MFMA) =====
#define BLD 520
__global__ __launch_bounds__(256)
void head1_k(const ushort* __restrict__ Hb, const ushort* __restrict__ c1Wb,
             const float* __restrict__ c1b, float* __restrict__ X1) {
    __shared__ __align__(16) ushort As[128 * LDT];
    __shared__ __align__(16) ushort Bs[32 * BLD];
    const int tid = threadIdx.x;
    const int lane = tid & 63, wave = tid >> 6;
    const int lm = lane & 15, quad = lane >> 4;
    const int m0 = blockIdx.x * 128;
#pragma unroll
    for (int u = 0; u < 8; u++) {
        int ii = tid + u * 256;
        int nrow = ii >> 6;
        int koff = (ii & 63) * 8;
        *(uint4*)&Bs[nrow * BLD + koff] = *(const uint4*)(c1Wb + nrow * 512 + koff);
    }
    f32x4 acc[2][2];
#pragma unroll
    for (int mt = 0; mt < 2; mt++)
#pragma unroll
        for (int nt = 0; nt < 2; nt++) acc[mt][nt] = (f32x4){0.f, 0.f, 0.f, 0.f};

    const int r = tid >> 1, half = tid & 1;
    for (int k0 = 0; k0 < 512; k0 += 32) {
        const ushort* s = Hb + (size_t)(m0 + r) * 512 + k0 + half * 16;
        uint4 v0 = *(const uint4*)s;
        uint4 v1 = *(const uint4*)(s + 8);
        __syncthreads();
        *(uint4*)&As[r * LDT + half * 16]     = v0;
        *(uint4*)&As[r * LDT + half * 16 + 8] = v1;
        __syncthreads();
        short8 af[2], bf[2];
#pragma unroll
        for (int mt = 0; mt < 2; mt++)
            af[mt] = *(const short8*)&As[(wave * 32 + mt * 16 + lm) * LDT + quad * 8];
#pragma unroll
        for (int nt = 0; nt < 2; nt++)
            bf[nt] = *(const short8*)&Bs[(nt * 16 + lm) * BLD + k0 + quad * 8];
#pragma unroll
        for (int mt = 0; mt < 2; mt++)
#pragma unroll
            for (int nt = 0; nt < 2; nt++)
                acc[mt][nt] = __builtin_amdgcn_mfma_f32_16x16x32_bf16(
                    af[mt], bf[nt], acc[mt][nt], 0, 0, 0);
    }
#pragma unroll
    for (int mt = 0; mt < 2; mt++) {
        int row0 = m0 + wave * 32 + mt * 16 + quad * 4;
#pragma unroll
        for (int nt = 0; nt < 2; nt++) {
            int col = nt * 16 + lm;
            float bia = c1b[col];
#pragma unroll
            for (int i = 0; i < 4; i++)
                X1[(size_t)(row0 + i) * 32 + col] = acc[mt][nt][i] + bia;
        }
    }
}

// ============ head stage 2: one thread per (bn,t) row ========================
__global__ __launch_bounds__(256)
void head2_k(const float* __restrict__ X1, int bn_base, int M,
             const float* __restrict__ g1, const float* __restrict__ b1,
             const float* __restrict__ m1, const float* __restrict__ v1,
             const float* __restrict__ c2W, const float* __restrict__ c2b,
             const float* __restrict__ g2, const float* __restrict__ b2,
             const float* __restrict__ m2, const float* __restrict__ v2,
             const float* __restrict__ c3W, const float* __restrict__ c3b,
             float* __restrict__ sum_dist, float* __restrict__ sum_score) {
    int row = blockIdx.x * 256 + threadIdx.x;
    if (row >= M) return;
    float x1[32], y1[32];
    const float* xr = X1 + (size_t)row * 32;
#pragma unroll
    for (int c = 0; c < 32; c++) x1[c] = xr[c];
    float d1 = 0.0f;
#pragma unroll
    for (int c = 0; c < 32; c++) {
        float dd = x1[c] - m1[c];
        d1 += dd * dd / v1[c];
        y1[c] = fmaxf(0.0f, dd * rsqrtf(v1[c] + LEPS) * g1[c] + b1[c]);
    }
    float d2 = 0.0f, sc = c3b[0];
#pragma unroll
    for (int o = 0; o < 16; o++) {
        float acc = c2b[o];
        const float* wr = c2W + o * 32;
#pragma unroll
        for (int c = 0; c < 32; c++) acc += wr[c] * y1[c];
        float dd = acc - m2[o];
        d2 += dd * dd / v2[o];
        float y2 = fmaxf(0.0f, dd * rsqrtf(v2[o] + LEPS) * g2[o] + b2[o]);
        sc += c3W[o] * y2;
    }
    float dist = sqrtf(d1) + sqrtf(d2);
    sc = 1.0f / (1.0f + expf(-sc));
    int bn = bn_base + (row >> 8);
    int t = row & 255;
    int b = bn / 10;
    atomicAdd(&sum_dist[b * T_ + t], dist);
    atomicAdd(&sum_score[b * T_ + t], sc);
}

// --------------------------------------------------------------- final out
__global__ void combine_k(const float* __restrict__ sd, const float* __restrict__ ss,
                          float* __restrict__ out) {
    int i = blockIdx.x * 256 + threadIdx.x;
    if (i < 16 * T_) out[i] = (sd[i] * 0.1f) * (ss[i] * 0.1f);
}

// ===========================================================================
extern "C" void kernel_launch(void* const* d_in, const int* in_sizes, int n_in,
                              void* d_out, int out_size, void* d_ws, size_t ws_size,
                              hipStream_t stream) {
    const float* x     = (const float*)d_in[0];
    const float* W_emb = (const float*)d_in[1];
    const float* b_emb = (const float*)d_in[2];
    const float* ln1_g = (const float*)d_in[3];
    const float* ln1_b = (const float*)d_in[4];
    const float* W_qkv = (const float*)d_in[5];
    const float* W_o   = (const float*)d_in[6];
    const float* b_o   = (const float*)d_in[7];
    const float* ln2_g = (const float*)d_in[8];
    const float* ln2_b = (const float*)d_in[9];
    const float* W_f1  = (const float*)d_in[10];
    const float* b_f1  = (const float*)d_in[11];
    const float* W_f2  = (const float*)d_in[12];
    const float* b_f2  = (const float*)d_in[13];
    const float* c1_W  = (const float*)d_in[14];
    const float* c1_b  = (const float*)d_in[15];
    const float* bn1_g = (const float*)d_in[16];
    const float* bn1_b = (const float*)d_in[17];
    const float* bn1_m = (const float*)d_in[18];
    const float* bn1_v = (const float*)d_in[19];
    const float* c2_W  = (const float*)d_in[20];
    const float* c2_b  = (const float*)d_in[21];
    const float* bn2_g = (const float*)d_in[22];
    const float* bn2_b = (const float*)d_in[23];
    const float* bn2_m = (const float*)d_in[24];
    const float* bn2_v = (const float*)d_in[25];
    const float* c3_W  = (const float*)d_in[26];
    const float* c3_b  = (const float*)d_in[27];
    float* out = (float*)d_out;

    // ---------------- workspace layout (runtime-chunked over bn) ----------
    char* p = (char*)d_ws;
    auto alloc = [&](size_t bytes) -> char* {
        char* q = p; p += (bytes + 255) & ~(size_t)255; return q;
    };
    ushort* wEmb = (ushort*)alloc((size_t)C_ * 3072 * 2);
    ushort* wQkv = (ushort*)alloc((size_t)2 * 2048 * 512 * 2);
    ushort* wO   = (ushort*)alloc((size_t)2 * 512 * 1024 * 2);
    ushort* wF1  = (ushort*)alloc((size_t)2 * 512 * 512 * 2);
    ushort* wF2  = (ushort*)alloc((size_t)2 * 512 * 512 * 2);
    ushort* A2bf = (ushort*)alloc((size_t)256 * 256 * 2);
    ushort* c1Wb = (ushort*)alloc((size_t)32 * 512 * 2);
    float*  s256      = (float*)alloc(256 * 4);
    float*  sum_dist  = (float*)alloc(4096 * 4);
    float*  sum_score = (float*)alloc(4096 * 4);
    size_t fixedB = (size_t)(p - (char*)d_ws);

    // per-row bytes: xb 2048 + h 1024 + z 1024 + qkvt 4096 + o 2048 + X1 128 = 10368
    int CH = 8;
    const int cands[7] = {160, 80, 40, 32, 20, 16, 10};
    for (int ci = 0; ci < 7; ci++) {
        size_t per = (size_t)cands[ci] * 256 * 10368 + 8192;
        if (fixedB + per <= ws_size) { CH = cands[ci]; break; }
    }
    const int MR = CH * 256;
    ushort* xb   = (ushort*)alloc((size_t)MR * 1024 * 2);
    ushort* h    = (ushort*)alloc((size_t)MR * 512 * 2);
    ushort* z    = (ushort*)alloc((size_t)MR * 512 * 2);
    ushort* qkvt = (ushort*)alloc((size_t)MR * 2048 * 2);
    ushort* o    = (ushort*)alloc((size_t)MR * 1024 * 2);
    ushort* g    = o;
    float*  X1   = (float*)alloc((size_t)MR * 32 * 4);

    // ---------------- once-per-launch prep ----------------
    zero_k<<<(8192 + 255) / 256, 256, 0, stream>>>(sum_dist, 8192);
    a2_colsum_k<<<1, 256, 0, stream>>>(s256);
    a2fill_k<<<256, 256, 0, stream>>>(s256, A2bf);
    wemb_k<<<(C_ * 3072 + 255) / 256, 256, 0, stream>>>(W_emb, wEmb);
    bcvt_k<<<(32 * 512 + 255) / 256, 256, 0, stream>>>(c1_W, c1Wb, 32 * 512);
    for (int l = 0; l < 2; l++) {
        tconv_k<<<(2048 * 512 + 255) / 256, 256, 0, stream>>>(
            W_qkv + (size_t)l * 512 * 2048, wQkv + (size_t)l * 2048 * 512, 512, 2048);
        tconv_k<<<(512 * 1024 + 255) / 256, 256, 0, stream>>>(
            W_o + (size_t)l * 1024 * 512, wO + (size_t)l * 512 * 1024, 1024, 512);
        tconv_k<<<(512 * 512 + 255) / 256, 256, 0, stream>>>(
            W_f1 + (size_t)l * 512 * 512, wF1 + (size_t)l * 512 * 512, 512, 512);
        tconv_k<<<(512 * 512 + 255) / 256, 256, 0, stream>>>(
            W_f2 + (size_t)l * 512 * 512, wF2 + (size_t)l * 512 * 512, 512, 512);
    }

    // ---------------- pipeline, chunked over bn ----------------
    for (int cs = 0; cs < BNB; cs += CH) {
        const float* xc = x + (size_t)cs * T_ * D_;

        // x chunk -> bf16
        int n4 = MR * 1024 / 4;
        xcvt_k<<<(n4 + 255) / 256, 256, 0, stream>>>(xc, xb, n4);

        // conv1d(k=3,pad=1)+ReLU as implicit-im2row MFMA GEMM -> h bf16
        gemm_k<1, 2, 0, 1><<<dim3(512 / 128, MR / 128), 256, 0, stream>>>(
            nullptr, wEmb, b_emb, nullptr, h, MR, 512, 3072, xb);

        for (int l = 0; l < 2; l++) {
            ln_k<<<MR, 256, 0, stream>>>(h, ln1_g + l * C_, ln1_b + l * C_, z);
            gemm_k<0, 0, 0, 1><<<dim3(2048 / 128, MR / 128), 256, 0, stream>>>(
                z, wQkv + (size_t)l * 2048 * 512, nullptr, nullptr, qkvt,
                MR, 2048, 512, nullptr);
            attn1_k<<<dim3(CH, H_), 256, 0, stream>>>(qkvt, o);
            attn2_k<<<dim3(4, 2, CH), 256, 0, stream>>>(A2bf, qkvt, o);
            gemm_k<0, 0, 1, 1><<<dim3(512 / 128, MR / 128), 256, 0, stream>>>(
                o, wO + (size_t)l * 512 * 1024, b_o + l * C_, h, h,
                MR, 512, 1024, nullptr);
            ln_k<<<MR, 256, 0, stream>>>(h, ln2_g + l * C_, ln2_b + l * C_, z);
            gemm_k<0, 1, 0, 1><<<dim3(512 / 128, MR / 128), 256, 0, stream>>>(
                z, wF1 + (size_t)l * 512 * 512, b_f1 + l * C_, nullptr, g,
                MR, 512, 512, nullptr);
            gemm_k<0, 0, 1, 1><<<dim3(512 / 128, MR / 128), 256, 0, stream>>>(
                g, wF2 + (size_t)l * 512 * 512, b_f2 + l * C_, h, h,
                MR, 512, 512, nullptr);
        }

        head1_k<<<MR / 128, 256, 0, stream>>>(h, c1Wb, c1_b, X1);
        head2_k<<<MR / 256, 256, 0, stream>>>(
            X1, cs, MR, bn1_g, bn1_b, bn1_m, bn1_v,
            c2_W, c2_b, bn2_g, bn2_b, bn2_m, bn2_v, c3_W, c3_b,
            sum_dist, sum_score);
    }

    combine_k<<<16, 256, 0, stream>>>(sum_dist, sum_score, out);
}

// Round 7
// 1778.420 us; speedup vs baseline: 14.6742x; 1.0350x over previous
//
#include <hip/hip_runtime.h>
#include <math.h>

#define T_    256
#define D_    1024
#define C_    512
#define H_    4
#define DH_   128
#define BNB   160
#define LEPS  1e-5f
#define INV_E 0.36787944117144233f
#define SCALE_ 0.08838834764831845f   // 1/sqrt(128)
#define LDT   40                      // LDS row stride (elems) for gemm tiles

typedef unsigned short ushort;
typedef unsigned int   uint;
typedef __attribute__((ext_vector_type(8))) short short8;   // 8 bf16 (4 VGPRs)
typedef __attribute__((ext_vector_type(4))) float f32x4;

__device__ __forceinline__ ushort f2b(float f) {            // fp32 -> bf16 RNE
    uint u = __float_as_uint(f);
    u += 0x7fffu + ((u >> 16) & 1u);
    return (ushort)(u >> 16);
}
__device__ __forceinline__ float b2f(ushort u) {
    return __uint_as_float(((uint)u) << 16);
}
__device__ __forceinline__ uint pk(float a, float b) {
    return (uint)f2b(a) | ((uint)f2b(b) << 16);
}

// ---------------------------------------------------------------- zero fill
__global__ void zero_k(float* __restrict__ p, int n) {
    int i = blockIdx.x * 256 + threadIdx.x;
    if (i < n) p[i] = 0.0f;
}

// ---------------- x fp32 -> bf16, 4 elems/thread
__global__ void xcvt_k(const float* __restrict__ src, ushort* __restrict__ dst, int n4) {
    int i = blockIdx.x * 256 + threadIdx.x;
    if (i < n4) {
        float4 f = ((const float4*)src)[i];
        uint2 v;
        v.x = pk(f.x, f.y);
        v.y = pk(f.z, f.w);
        ((uint2*)dst)[i] = v;
    }
}

// ---------------- generic transpose+convert: src (K,N) fp32 -> dst (N,K) bf16
__global__ void tconv_k(const float* __restrict__ src, ushort* __restrict__ dst,
                        int K, int N) {
    int idx = blockIdx.x * 256 + threadIdx.x;
    if (idx >= N * K) return;
    int n = idx / K, k = idx % K;
    dst[idx] = f2b(src[(size_t)k * N + n]);
}

// ---------------- elementwise fp32 -> bf16 convert
__global__ void bcvt_k(const float* __restrict__ src, ushort* __restrict__ dst, int n) {
    int i = blockIdx.x * 256 + threadIdx.x;
    if (i < n) dst[i] = f2b(src[i]);
}

// -------- W_emb (C,1024,3) -> bf16 [C][3072] with k = dt*1024+ci ordering
__global__ void wemb_k(const float* __restrict__ W, ushort* __restrict__ Wt) {
    int idx = blockIdx.x * 256 + threadIdx.x;
    if (idx >= C_ * 3072) return;
    int c = idx / 3072, k = idx % 3072;
    int dt = k >> 10, ci = k & 1023;
    Wt[idx] = f2b(W[(size_t)c * 3072 + ci * 3 + dt]);
}

// -------------------------------- s[j] = sum_k exp(-|j-k|/e)  (a2 col sums)
__global__ void a2_colsum_k(float* __restrict__ s) {
    int j = threadIdx.x;
    float acc = 0.0f;
    for (int k = 0; k < T_; k++) acc += expf(-fabsf((float)(j - k)) * INV_E);
    s[j] = acc;
}

// -------------------------------- A2 bf16 [i][j] = exp(-|i-j|/e)/s[j]
__global__ void a2fill_k(const float* __restrict__ s, ushort* __restrict__ A2) {
    int i = blockIdx.x, j = threadIdx.x;
    A2[i * 256 + j] = f2b(expf(-fabsf((float)(i - j)) * INV_E) / s[j]);
}

// ------------------------------------------- LayerNorm, bf16 in -> bf16 out
__global__ __launch_bounds__(256)
void ln_k(const ushort* __restrict__ X, const float* __restrict__ g,
          const float* __restrict__ b, ushort* __restrict__ Z) {
    int row = blockIdx.x;
    int tid = threadIdx.x;
    const ushort* xr = X + (size_t)row * C_;
    float x0 = b2f(xr[tid]), x1 = b2f(xr[tid + 256]);
    __shared__ float red[256];
    red[tid] = x0 + x1;
    __syncthreads();
    for (int s = 128; s >= 1; s >>= 1) {
        if (tid < s) red[tid] += red[tid + s];
        __syncthreads();
    }
    float mean = red[0] * (1.0f / C_);
    __syncthreads();
    float d0 = x0 - mean, d1 = x1 - mean;
    red[tid] = d0 * d0 + d1 * d1;
    __syncthreads();
    for (int s = 128; s >= 1; s >>= 1) {
        if (tid < s) red[tid] += red[tid + s];
        __syncthreads();
    }
    float rinv = rsqrtf(red[0] * (1.0f / C_) + LEPS);
    ushort* zr = Z + (size_t)row * C_;
    zr[tid]       = f2b(d0 * rinv * g[tid]       + b[tid]);
    zr[tid + 256] = f2b(d1 * rinv * g[tid + 256] + b[tid + 256]);
}

// ======================= bf16 MFMA GEMM, 128x128 tile, BK=32 ================
// C(MxN) = A(MxK,bf16) @ B'(NxK,bf16)  [+bias] [ACT 1=gelu 2=relu] [+R bf16]
// CONV=1: A implicit im2row of Xb (bf16, chunk-local, k = dt*1024+ci)
// Block swizzle: all N-panels of one M-tile -> same XCD (idx ≡ mod 8) for L2 reuse.
template<int CONV, int ACT, int RESID, int OUTBF>
__global__ __launch_bounds__(256)
void gemm_k(const ushort* __restrict__ A, const ushort* __restrict__ B,
            const float* __restrict__ bias, const ushort* __restrict__ R,
            void* __restrict__ Cout, int M, int N, int K,
            const ushort* __restrict__ Xb) {
    __shared__ __align__(16) ushort As[128 * LDT];
    __shared__ __align__(16) ushort Bs[128 * LDT];
    const int tid  = threadIdx.x;
    const int lane = tid & 63, wave = tid >> 6;
    const int wr = wave >> 1, wc = wave & 1;
    const int lm = lane & 15, quad = lane >> 4;

    // ---- XCD-aware swizzle ----
    const int NP = gridDim.x, My = gridDim.y;
    int m_idx, n_idx;
    if ((My & 7) == 0) {
        int bid = blockIdx.y * NP + blockIdx.x;
        m_idx = (bid & 7) + 8 * (bid / (8 * NP));
        n_idx = (bid >> 3) % NP;
    } else {
        m_idx = blockIdx.y; n_idx = blockIdx.x;
    }
    const int m0 = m_idx * 128, n0 = n_idx * 128;
    const int r  = tid >> 1;
    const int c0 = (tid & 1) * 2;

    f32x4 acc[4][4];
#pragma unroll
    for (int mt = 0; mt < 4; mt++)
#pragma unroll
        for (int nt = 0; nt < 4; nt++) acc[mt][nt] = (f32x4){0.f, 0.f, 0.f, 0.f};

    for (int k0 = 0; k0 < K; k0 += 32) {
        if (CONV) {
            int g = m0 + r, bn = g >> 8, t = g & 255;
#pragma unroll
            for (int cc = 0; cc < 2; cc++) {
                int c = c0 + cc;
                int kc = k0 + c * 8;
                int dt = kc >> 10, ci = kc & 1023;
                int tt = t + dt - 1;
                uint4 val;
                if (tt >= 0 && tt < T_) {
                    val = *(const uint4*)(Xb + ((size_t)bn * T_ + tt) * D_ + ci);
                } else {
                    val.x = 0u; val.y = 0u; val.z = 0u; val.w = 0u;
                }
                *(uint4*)&As[r * LDT + c * 8] = val;
            }
        } else {
            const ushort* Arow = A + (size_t)(m0 + r) * K + k0;
            *(uint4*)&As[r * LDT + c0 * 8]       = *(const uint4*)(Arow + c0 * 8);
            *(uint4*)&As[r * LDT + (c0 + 1) * 8] = *(const uint4*)(Arow + (c0 + 1) * 8);
        }
        {
            const ushort* Brow = B + (size_t)(n0 + r) * K + k0;
            *(uint4*)&Bs[r * LDT + c0 * 8]       = *(const uint4*)(Brow + c0 * 8);
            *(uint4*)&Bs[r * LDT + (c0 + 1) * 8] = *(const uint4*)(Brow + (c0 + 1) * 8);
        }
        __syncthreads();
        short8 af[4], bfv[4];
#pragma unroll
        for (int mt = 0; mt < 4; mt++)
            af[mt] = *(const short8*)&As[(wr * 64 + mt * 16 + lm) * LDT + quad * 8];
#pragma unroll
        for (int nt = 0; nt < 4; nt++)
            bfv[nt] = *(const short8*)&Bs[(wc * 64 + nt * 16 + lm) * LDT + quad * 8];
#pragma unroll
        for (int mt = 0; mt < 4; mt++)
#pragma unroll
            for (int nt = 0; nt < 4; nt++)
                acc[mt][nt] = __builtin_amdgcn_mfma_f32_16x16x32_bf16(
                    af[mt], bfv[nt], acc[mt][nt], 0, 0, 0);
        __syncthreads();
    }

#pragma unroll
    for (int mt = 0; mt < 4; mt++) {
        int grow0 = m0 + wr * 64 + mt * 16 + quad * 4;
#pragma unroll
        for (int nt = 0; nt < 4; nt++) {
            int gcol = n0 + wc * 64 + nt * 16 + lm;
            float bia = bias ? bias[gcol] : 0.0f;
            f32x4 v = acc[mt][nt];
#pragma unroll
            for (int i = 0; i < 4; i++) {
                int grow = grow0 + i;
                float val = v[i] + bia;
                if (ACT == 1) val = val * 0.5f * (1.0f + erff(val * 0.70710678118654752f));
                if (ACT == 2) val = fmaxf(val, 0.0f);
                if (RESID) val += b2f(R[(size_t)grow * N + gcol]);
                if (OUTBF) ((ushort*)Cout)[(size_t)grow * N + gcol] = f2b(val);
                else       ((float*)Cout)[(size_t)grow * N + gcol]  = val;
            }
        }
    }
}

// ================= flash-style softmax attention (o1 half), MFMA ============
__global__ __launch_bounds__(256)
void attn1_k(const ushort* __restrict__ qkvt, ushort* __restrict__ O) {
    const int bn = blockIdx.x, h = blockIdx.y;
    const int tid = threadIdx.x;
    const int wave = tid >> 6, lane = tid & 63;
    const int lm = lane & 15, quad = lane >> 4;
    __shared__ __align__(16) ushort Ks[32 * 136];
    __shared__ __align__(16) ushort Vt[128 * 40];
    __shared__ __align__(16) ushort Ps[4][64 * 40];
    const ushort* base = qkvt + (size_t)bn * T_ * 2048;

    short8 aq[4][4];
#pragma unroll
    for (int mt = 0; mt < 4; mt++) {
        const ushort* qrow = base + (size_t)(wave * 64 + mt * 16 + lm) * 2048 + h * DH_;
#pragma unroll
        for (int ks = 0; ks < 4; ks++)
            aq[mt][ks] = *(const short8*)(qrow + ks * 32 + quad * 8);
    }

    f32x4 oacc[4][8];
#pragma unroll
    for (int mt = 0; mt < 4; mt++)
#pragma unroll
        for (int nt = 0; nt < 8; nt++) oacc[mt][nt] = (f32x4){0.f, 0.f, 0.f, 0.f};
    float mrow[4][4], lrow[4][4];
#pragma unroll
    for (int mt = 0; mt < 4; mt++)
#pragma unroll
        for (int i = 0; i < 4; i++) { mrow[mt][i] = -1e30f; lrow[mt][i] = 0.0f; }

    for (int kt = 0; kt < 8; kt++) {
        __syncthreads();
#pragma unroll
        for (int u = 0; u < 2; u++) {
            int ii = tid + u * 256;
            int j = ii >> 4, dc = ii & 15;
            *(uint4*)&Ks[j * 136 + dc * 8] =
                *(const uint4*)(base + (size_t)(kt * 32 + j) * 2048 + 512 + h * DH_ + dc * 8);
        }
        {
            int j = tid & 31, half = tid >> 5;
            const ushort* vrow = base + (size_t)(kt * 32 + j) * 2048 + 1024 + h * DH_ + half * 16;
            uint4 v0 = *(const uint4*)vrow;
            uint4 v1 = *(const uint4*)(vrow + 8);
            ushort e[16];
            *(uint4*)&e[0] = v0; *(uint4*)&e[8] = v1;
#pragma unroll
            for (int u = 0; u < 16; u++)
                Vt[(half * 16 + u) * 40 + j] = e[u];
        }
        __syncthreads();

        f32x4 s[4][2];
#pragma unroll
        for (int mt = 0; mt < 4; mt++)
#pragma unroll
            for (int nt = 0; nt < 2; nt++) s[mt][nt] = (f32x4){0.f, 0.f, 0.f, 0.f};
#pragma unroll
        for (int ks = 0; ks < 4; ks++) {
            short8 bk0 = *(const short8*)&Ks[lm * 136 + ks * 32 + quad * 8];
            short8 bk1 = *(const short8*)&Ks[(16 + lm) * 136 + ks * 32 + quad * 8];
#pragma unroll
            for (int mt = 0; mt < 4; mt++) {
                s[mt][0] = __builtin_amdgcn_mfma_f32_16x16x32_bf16(aq[mt][ks], bk0, s[mt][0], 0, 0, 0);
                s[mt][1] = __builtin_amdgcn_mfma_f32_16x16x32_bf16(aq[mt][ks], bk1, s[mt][1], 0, 0, 0);
            }
        }

#pragma unroll
        for (int mt = 0; mt < 4; mt++) {
#pragma unroll
            for (int i = 0; i < 4; i++) {
                float v0 = s[mt][0][i] * SCALE_;
                float v1 = s[mt][1][i] * SCALE_;
                float rmax = fmaxf(v0, v1);
#pragma unroll
                for (int mk = 1; mk < 16; mk <<= 1)
                    rmax = fmaxf(rmax, __shfl_xor(rmax, mk));
                float mold = mrow[mt][i];
                float mnew = fmaxf(mold, rmax);
                float alpha = __expf(mold - mnew);
                float p0 = __expf(v0 - mnew);
                float p1 = __expf(v1 - mnew);
                float rs = p0 + p1;
#pragma unroll
                for (int mk = 1; mk < 16; mk <<= 1)
                    rs += __shfl_xor(rs, mk);
                lrow[mt][i] = lrow[mt][i] * alpha + rs;
                mrow[mt][i] = mnew;
#pragma unroll
                for (int nt = 0; nt < 8; nt++) {
                    oacc[mt][nt][i] *= alpha;
                }
                int prow = mt * 16 + quad * 4 + i;
                Ps[wave][prow * 40 + lm]      = f2b(p0);
                Ps[wave][prow * 40 + 16 + lm] = f2b(p1);
            }
        }

        short8 ap[4];
#pragma unroll
        for (int mt = 0; mt < 4; mt++)
            ap[mt] = *(const short8*)&Ps[wave][(mt * 16 + lm) * 40 + quad * 8];
#pragma unroll
        for (int nt = 0; nt < 8; nt++) {
            short8 bv = *(const short8*)&Vt[(nt * 16 + lm) * 40 + quad * 8];
#pragma unroll
            for (int mt = 0; mt < 4; mt++)
                oacc[mt][nt] = __builtin_amdgcn_mfma_f32_16x16x32_bf16(ap[mt], bv, oacc[mt][nt], 0, 0, 0);
        }
    }

#pragma unroll
    for (int mt = 0; mt < 4; mt++) {
#pragma unroll
        for (int i = 0; i < 4; i++) {
            int row = wave * 64 + mt * 16 + quad * 4 + i;
            float rinv = 1.0f / lrow[mt][i];
#pragma unroll
            for (int nt = 0; nt < 8; nt++) {
                int d = nt * 16 + lm;
                O[((size_t)bn * T_ + row) * 1024 + h * 256 + d] =
                    f2b(oacc[mt][nt][i] * rinv);
            }
        }
    }
}

// ================= decay attention (o2 half): o2 = A2 @ T, batched over bn ==
__global__ __launch_bounds__(256)
void attn2_k(const ushort* __restrict__ A2, const ushort* __restrict__ qkvt,
             ushort* __restrict__ O) {
    __shared__ __align__(16) ushort As[128 * LDT];
    __shared__ __align__(16) ushort Bs[128 * 48];
    const int tid = threadIdx.x;
    const int bn = blockIdx.z;
    const int m0 = blockIdx.y * 128;
    const int n0 = blockIdx.x * 128;
    const int lane = tid & 63, wave = tid >> 6;
    const int wr = wave >> 1, wc = wave & 1;
    const int lm = lane & 15, quad = lane >> 4;
    const ushort* tbase = qkvt + (size_t)bn * T_ * 2048 + 1536;
    const int r = tid >> 1, c0 = (tid & 1) * 2;

    f32x4 acc[4][4];
#pragma unroll
    for (int mt = 0; mt < 4; mt++)
#pragma unroll
        for (int nt = 0; nt < 4; nt++) acc[mt][nt] = (f32x4){0.f, 0.f, 0.f, 0.f};

    for (int k0 = 0; k0 < 256; k0 += 32) {
        const ushort* Arow = A2 + (size_t)(m0 + r) * 256 + k0;
        *(uint4*)&As[r * LDT + c0 * 8]       = *(const uint4*)(Arow + c0 * 8);
        *(uint4*)&As[r * LDT + (c0 + 1) * 8] = *(const uint4*)(Arow + (c0 + 1) * 8);
        {
            int kr = tid & 31, np = tid >> 5;
            const ushort* trow = tbase + (size_t)(k0 + kr) * 2048 + n0 + np * 16;
            uint4 v0 = *(const uint4*)trow;
            uint4 v1 = *(const uint4*)(trow + 8);
            ushort e[16];
            *(uint4*)&e[0] = v0; *(uint4*)&e[8] = v1;
#pragma unroll
            for (int u = 0; u < 16; u++)
                Bs[(np * 16 + u) * 48 + kr] = e[u];
        }
        __syncthreads();
        short8 af[4], bf[4];
#pragma unroll
        for (int mt = 0; mt < 4; mt++)
            af[mt] = *(const short8*)&As[(wr * 64 + mt * 16 + lm) * LDT + quad * 8];
#pragma unroll
        for (int nt = 0; nt < 4; nt++)
            bf[nt] = *(const short8*)&Bs[(wc * 64 + nt * 16 + lm) * 48 + quad * 8];
#pragma unroll
        for (int mt = 0; mt < 4; mt++)
#pragma unroll
            for (int nt = 0; nt < 4; nt++)
                acc[mt][nt] = __builtin_amdgcn_mfma_f32_16x16x32_bf16(
                    af[mt], bf[nt], acc[mt][nt], 0, 0, 0);
        __syncthreads();
    }

#pragma unroll
    for (int mt = 0; mt < 4; mt++) {
        int row0 = m0 + wr * 64 + mt * 16 + quad * 4;
#pragma unroll
        for (int nt = 0; nt < 4; nt++) {
            int n = n0 + wc * 64 + nt * 16 + lm;
            int h = n >> 7, d = n & 127;
#pragma unroll
            for (int i = 0; i < 4; i++) {
                int row = row0 + i;
                O[((size_t)bn * T_ + row) * 1024 + h * 256 + 128 + d] =
                    f2b(acc[mt][nt][i]);
            }
        }
    }
}

// ============ head stage 1: x1 = h @ c1W^T + c1b  (M x 32, K=512, MFMA) =====
#define BLD 520
__global__ __launch_bounds__(256)
void head1_k(const ushort* __restrict__ Hb, const ushort* __restrict__ c1Wb,
             const float* __restrict__ c1b, float* __restrict__ X1) {
    __shared__ __align__(16) ushort As[128 * LDT];
    __shared__ __align__(16) ushort Bs[32 * BLD];
    const int tid = threadIdx.x;
    const int lane = tid & 63, wave = tid >> 6;
    const int lm = lane & 15, quad = lane >> 4;
    const int m0 = blockIdx.x * 128;
#pragma unroll
    for (int u = 0; u < 8; u++) {
        int ii = tid + u * 256;
        int nrow = ii >> 6;
        int koff = (ii & 63) * 8;
        *(uint4*)&Bs[nrow * BLD + koff] = *(const uint4*)(c1Wb + nrow * 512 + koff);
    }
    f32x4 acc[2][2];
#pragma unroll
    for (int mt = 0; mt < 2; mt++)
#pragma unroll
        for (int nt = 0; nt < 2; nt++) acc[mt][nt] = (f32x4){0.f, 0.f, 0.f, 0.f};

    const int r = tid >> 1, half = tid & 1;
    for (int k0 = 0; k0 < 512; k0 += 32) {
        const ushort* s = Hb + (size_t)(m0 + r) * 512 + k0 + half * 16;
        uint4 v0 = *(const uint4*)s;
        uint4 v1 = *(const uint4*)(s + 8);
        __syncthreads();
        *(uint4*)&As[r * LDT + half * 16]     = v0;
        *(uint4*)&As[r * LDT + half * 16 + 8] = v1;
        __syncthreads();
        short8 af[2], bf[2];
#pragma unroll
        for (int mt = 0; mt < 2; mt++)
            af[mt] = *(const short8*)&As[(wave * 32 + mt * 16 + lm) * LDT + quad * 8];
#pragma unroll
        for (int nt = 0; nt < 2; nt++)
            bf[nt] = *(const short8*)&Bs[(nt * 16 + lm) * BLD + k0 + quad * 8];
#pragma unroll
        for (int mt = 0; mt < 2; mt++)
#pragma unroll
            for (int nt = 0; nt < 2; nt++)
                acc[mt][nt] = __builtin_amdgcn_mfma_f32_16x16x32_bf16(
                    af[mt], bf[nt], acc[mt][nt], 0, 0, 0);
    }
#pragma unroll
    for (int mt = 0; mt < 2; mt++) {
        int row0 = m0 + wave * 32 + mt * 16 + quad * 4;
#pragma unroll
        for (int nt = 0; nt < 2; nt++) {
            int col = nt * 16 + lm;
            float bia = c1b[col];
#pragma unroll
            for (int i = 0; i < 4; i++)
                X1[(size_t)(row0 + i) * 32 + col] = acc[mt][nt][i] + bia;
        }
    }
}

// ============ head stage 2: one thread per (bn,t) row ========================
__global__ __launch_bounds__(256)
void head2_k(const float* __restrict__ X1, int bn_base, int M,
             const float* __restrict__ g1, const float* __restrict__ b1,
             const float* __restrict__ m1, const float* __restrict__ v1,
             const float* __restrict__ c2W, const float* __restrict__ c2b,
             const float* __restrict__ g2, const float* __restrict__ b2,
             const float* __restrict__ m2, const float* __restrict__ v2,
             const float* __restrict__ c3W, const float* __restrict__ c3b,
             float* __restrict__ sum_dist, float* __restrict__ sum_score) {
    int row = blockIdx.x * 256 + threadIdx.x;
    if (row >= M) return;
    float x1[32], y1[32];
    const float* xr = X1 + (size_t)row * 32;
#pragma unroll
    for (int c = 0; c < 32; c++) x1[c] = xr[c];
    float d1 = 0.0f;
#pragma unroll
    for (int c = 0; c < 32; c++) {
        float dd = x1[c] - m1[c];
        d1 += dd * dd / v1[c];
        y1[c] = fmaxf(0.0f, dd * rsqrtf(v1[c] + LEPS) * g1[c] + b1[c]);
    }
    float d2 = 0.0f, sc = c3b[0];
#pragma unroll
    for (int o = 0; o < 16; o++) {
        float acc = c2b[o];
        const float* wr = c2W + o * 32;
#pragma unroll
        for (int c = 0; c < 32; c++) acc += wr[c] * y1[c];
        float dd = acc - m2[o];
        d2 += dd * dd / v2[o];
        float y2 = fmaxf(0.0f, dd * rsqrtf(v2[o] + LEPS) * g2[o] + b2[o]);
        sc += c3W[o] * y2;
    }
    float dist = sqrtf(d1) + sqrtf(d2);
    sc = 1.0f / (1.0f + expf(-sc));
    int bn = bn_base + (row >> 8);
    int t = row & 255;
    int b = bn / 10;
    atomicAdd(&sum_dist[b * T_ + t], dist);
    atomicAdd(&sum_score[b * T_ + t], sc);
}

// --------------------------------------------------------------- final out
__global__ void combine_k(const float* __restrict__ sd, const float* __restrict__ ss,
                          float* __restrict__ out) {
    int i = blockIdx.x * 256 + threadIdx.x;
    if (i < 16 * T_) out[i] = (sd[i] * 0.1f) * (ss[i] * 0.1f);
}

// ===========================================================================
extern "C" void kernel_launch(void* const* d_in, const int* in_sizes, int n_in,
                              void* d_out, int out_size, void* d_ws, size_t ws_size,
                              hipStream_t stream) {
    const float* x     = (const float*)d_in[0];
    const float* W_emb = (const float*)d_in[1];
    const float* b_emb = (const float*)d_in[2];
    const float* ln1_g = (const float*)d_in[3];
    const float* ln1_b = (const float*)d_in[4];
    const float* W_qkv = (const float*)d_in[5];
    const float* W_o   = (const float*)d_in[6];
    const float* b_o   = (const float*)d_in[7];
    const float* ln2_g = (const float*)d_in[8];
    const float* ln2_b = (const float*)d_in[9];
    const float* W_f1  = (const float*)d_in[10];
    const float* b_f1  = (const float*)d_in[11];
    const float* W_f2  = (const float*)d_in[12];
    const float* b_f2  = (const float*)d_in[13];
    const float* c1_W  = (const float*)d_in[14];
    const float* c1_b  = (const float*)d_in[15];
    const float* bn1_g = (const float*)d_in[16];
    const float* bn1_b = (const float*)d_in[17];
    const float* bn1_m = (const float*)d_in[18];
    const float* bn1_v = (const float*)d_in[19];
    const float* c2_W  = (const float*)d_in[20];
    const float* c2_b  = (const float*)d_in[21];
    const float* bn2_g = (const float*)d_in[22];
    const float* bn2_b = (const float*)d_in[23];
    const float* bn2_m = (const float*)d_in[24];
    const float* bn2_v = (const float*)d_in[25];
    const float* c3_W  = (const float*)d_in[26];
    const float* c3_b  = (const float*)d_in[27];
    float* out = (float*)d_out;

    // ---------------- workspace layout (runtime-chunked over bn) ----------
    char* p = (char*)d_ws;
    auto alloc = [&](size_t bytes) -> char* {
        char* q = p; p += (bytes + 255) & ~(size_t)255; return q;
    };
    ushort* wEmb = (ushort*)alloc((size_t)C_ * 3072 * 2);
    ushort* wQkv = (ushort*)alloc((size_t)2 * 2048 * 512 * 2);
    ushort* wO   = (ushort*)alloc((size_t)2 * 512 * 1024 * 2);
    ushort* wF1  = (ushort*)alloc((size_t)2 * 512 * 512 * 2);
    ushort* wF2  = (ushort*)alloc((size_t)2 * 512 * 512 * 2);
    ushort* A2bf = (ushort*)alloc((size_t)256 * 256 * 2);
    ushort* c1Wb = (ushort*)alloc((size_t)32 * 512 * 2);
    float*  s256      = (float*)alloc(256 * 4);
    float*  sum_dist  = (float*)alloc(4096 * 4);
    float*  sum_score = (float*)alloc(4096 * 4);
    size_t fixedB = (size_t)(p - (char*)d_ws);

    // per-row bytes: xb 2048 + h 1024 + z 1024 + qkvt 4096 + o 2048 + X1 128 = 10368
    int CH = 8;
    const int cands[7] = {160, 80, 40, 32, 20, 16, 10};
    for (int ci = 0; ci < 7; ci++) {
        size_t per = (size_t)cands[ci] * 256 * 10368 + 8192;
        if (fixedB + per <= ws_size) { CH = cands[ci]; break; }
    }
    const int MR = CH * 256;
    ushort* xb   = (ushort*)alloc((size_t)MR * 1024 * 2);
    ushort* h    = (ushort*)alloc((size_t)MR * 512 * 2);
    ushort* z    = (ushort*)alloc((size_t)MR * 512 * 2);
    ushort* qkvt = (ushort*)alloc((size_t)MR * 2048 * 2);
    ushort* o    = (ushort*)alloc((size_t)MR * 1024 * 2);
    ushort* g    = o;
    float*  X1   = (float*)alloc((size_t)MR * 32 * 4);

    // ---------------- once-per-launch prep ----------------
    zero_k<<<(8192 + 255) / 256, 256, 0, stream>>>(sum_dist, 8192);
    a2_colsum_k<<<1, 256, 0, stream>>>(s256);
    a2fill_k<<<256, 256, 0, stream>>>(s256, A2bf);
    wemb_k<<<(C_ * 3072 + 255) / 256, 256, 0, stream>>>(W_emb, wEmb);
    bcvt_k<<<(32 * 512 + 255) / 256, 256, 0, stream>>>(c1_W, c1Wb, 32 * 512);
    for (int l = 0; l < 2; l++) {
        tconv_k<<<(2048 * 512 + 255) / 256, 256, 0, stream>>>(
            W_qkv + (size_t)l * 512 * 2048, wQkv + (size_t)l * 2048 * 512, 512, 2048);
        tconv_k<<<(512 * 1024 + 255) / 256, 256, 0, stream>>>(
            W_o + (size_t)l * 1024 * 512, wO + (size_t)l * 512 * 1024, 1024, 512);
        tconv_k<<<(512 * 512 + 255) / 256, 256, 0, stream>>>(
            W_f1 + (size_t)l * 512 * 512, wF1 + (size_t)l * 512 * 512, 512, 512);
        tconv_k<<<(512 * 512 + 255) / 256, 256, 0, stream>>>(
            W_f2 + (size_t)l * 512 * 512, wF2 + (size_t)l * 512 * 512, 512, 512);
    }

    // ---------------- pipeline, chunked over bn ----------------
    for (int cs = 0; cs < BNB; cs += CH) {
        const float* xc = x + (size_t)cs * T_ * D_;

        // x chunk -> bf16
        int n4 = MR * 1024 / 4;
        xcvt_k<<<(n4 + 255) / 256, 256, 0, stream>>>(xc, xb, n4);

        // conv1d(k=3,pad=1)+ReLU as implicit-im2row MFMA GEMM -> h bf16
        gemm_k<1, 2, 0, 1><<<dim3(512 / 128, MR / 128), 256, 0, stream>>>(
            nullptr, wEmb, b_emb, nullptr, h, MR, 512, 3072, xb);

        for (int l = 0; l < 2; l++) {
            ln_k<<<MR, 256, 0, stream>>>(h, ln1_g + l * C_, ln1_b + l * C_, z);
            gemm_k<0, 0, 0, 1><<<dim3(2048 / 128, MR / 128), 256, 0, stream>>>(
                z, wQkv + (size_t)l * 2048 * 512, nullptr, nullptr, qkvt,
                MR, 2048, 512, nullptr);
            attn1_k<<<dim3(CH, H_), 256, 0, stream>>>(qkvt, o);
            attn2_k<<<dim3(4, 2, CH), 256, 0, stream>>>(A2bf, qkvt, o);
            gemm_k<0, 0, 1, 1><<<dim3(512 / 128, MR / 128), 256, 0, stream>>>(
                o, wO + (size_t)l * 512 * 1024, b_o + l * C_, h, h,
                MR, 512, 1024, nullptr);
            ln_k<<<MR, 256, 0, stream>>>(h, ln2_g + l * C_, ln2_b + l * C_, z);
            gemm_k<0, 1, 0, 1><<<dim3(512 / 128, MR / 128), 256, 0, stream>>>(
                z, wF1 + (size_t)l * 512 * 512, b_f1 + l * C_, nullptr, g,
                MR, 512, 512, nullptr);
            gemm_k<0, 0, 1, 1><<<dim3(512 / 128, MR / 128), 256, 0, stream>>>(
                g, wF2 + (size_t)l * 512 * 512, b_f2 + l * C_, h, h,
                MR, 512, 512, nullptr);
        }

        head1_k<<<MR / 128, 256, 0, stream>>>(h, c1Wb, c1_b, X1);
        head2_k<<<MR / 256, 256, 0, stream>>>(
            X1, cs, MR, bn1_g, bn1_b, bn1_m, bn1_v,
            c2_W, c2_b, bn2_g, bn2_b, bn2_m, bn2_v, c3_W, c3_b,
            sum_dist, sum_score);
    }

    combine_k<<<16, 256, 0, stream>>>(sum_dist, sum_score, out);
}

// Round 9
// 1588.538 us; speedup vs baseline: 16.4283x; 1.1195x over previous
//
#include <hip/hip_runtime.h>
#include <math.h>

#define T_    256
#define D_    1024
#define C_    512
#define H_    4
#define DH_   128
#define BNB   160
#define LEPS  1e-5f
#define INV_E 0.36787944117144233f
#define SCALE_ 0.08838834764831845f   // 1/sqrt(128)
#define LDT   40                      // padded LDS stride (attn/head kernels)
#define XROW  264192                  // padded x row block: 258*1024 elems per bn

typedef unsigned short ushort;
typedef unsigned int   uint;
typedef __attribute__((ext_vector_type(8))) short short8;   // 8 bf16 (4 VGPRs)
typedef __attribute__((ext_vector_type(4))) float f32x4;

__device__ __forceinline__ ushort f2b(float f) {            // fp32 -> bf16 RNE
    uint u = __float_as_uint(f);
    u += 0x7fffu + ((u >> 16) & 1u);
    return (ushort)(u >> 16);
}
__device__ __forceinline__ float b2f(ushort u) {
    return __uint_as_float(((uint)u) << 16);
}
__device__ __forceinline__ uint pk(float a, float b) {
    return (uint)f2b(a) | ((uint)f2b(b) << 16);
}
// async global->LDS DMA, 16B/lane; lds dest is wave-uniform base (+lane*16 by HW)
__device__ __forceinline__ void gl2lds(const void* g, void* l) {
    __builtin_amdgcn_global_load_lds(
        (const __attribute__((address_space(1))) void*)g,
        (__attribute__((address_space(3))) void*)l, 16, 0, 0);
}

// ---------------------------------------------------------------- zero fill
__global__ void zero_k(float* __restrict__ p, int n) {
    int i = blockIdx.x * 256 + threadIdx.x;
    if (i < n) p[i] = 0.0f;
}

// ---------------- x fp32 -> bf16 into padded layout [bn][258][1024], data at row t+1
__global__ void xcvt_k(const float* __restrict__ src, ushort* __restrict__ dst, int n4) {
    int i = blockIdx.x * 256 + threadIdx.x;
    if (i < n4) {
        float4 f = ((const float4*)src)[i];
        uint2 v;
        v.x = pk(f.x, f.y);
        v.y = pk(f.z, f.w);
        int e   = i * 4;
        int bn  = e >> 18;            // 262144 elems per bn
        int rem = e & 262143;
        ((uint2*)(dst + (size_t)bn * XROW + 1024 + rem))[0] = v;
    }
}

// ---------------- zero the pad rows (rows 0 and 257 of each bn)
__global__ void xpad_k(ushort* __restrict__ dst, int nbn) {
    int i = blockIdx.x * 256 + threadIdx.x;
    if (i >= nbn * 1024) return;
    int bn = i >> 10, j = i & 1023;
    int r = j >> 9, c = j & 511;
    uint* base = (uint*)(dst + (size_t)bn * XROW);
    // row 0 at uint 0; row 257 at uint (XROW-1024)/2  [BUGFIX: was (XROW-2048)/2 = row 256]
    base[(r ? (XROW - 1024) / 2 : 0) + c] = 0u;
}

// ---------------- tiled transpose+convert: src (K,N) fp32 -> dst (N,K) bf16
__global__ __launch_bounds__(256)
void tconv_k(const float* __restrict__ src, ushort* __restrict__ dst,
             int K, int N) {
    __shared__ float tile[32][33];
    int kb = blockIdx.x * 32, nb = blockIdx.y * 32;
    int tx = threadIdx.x & 31, ty = threadIdx.x >> 5;   // 32 x 8
#pragma unroll
    for (int i = 0; i < 32; i += 8)
        tile[ty + i][tx] = src[(size_t)(kb + ty + i) * N + nb + tx];
    __syncthreads();
#pragma unroll
    for (int i = 0; i < 32; i += 8)
        dst[(size_t)(nb + ty + i) * K + kb + tx] = f2b(tile[tx][ty + i]);
}

// ---------------- elementwise fp32 -> bf16 convert
__global__ void bcvt_k(const float* __restrict__ src, ushort* __restrict__ dst, int n) {
    int i = blockIdx.x * 256 + threadIdx.x;
    if (i < n) dst[i] = f2b(src[i]);
}

// -------- W_emb (C,1024,3) -> bf16 [C][3072] with k = dt*1024+ci ordering
__global__ void wemb_k(const float* __restrict__ W, ushort* __restrict__ Wt) {
    int idx = blockIdx.x * 256 + threadIdx.x;
    if (idx >= C_ * 3072) return;
    int c = idx / 3072, k = idx % 3072;
    int dt = k >> 10, ci = k & 1023;
    Wt[idx] = f2b(W[(size_t)c * 3072 + ci * 3 + dt]);
}

// -------------------------------- s[j] = sum_k exp(-|j-k|/e)  (a2 col sums)
__global__ void a2_colsum_k(float* __restrict__ s) {
    int j = threadIdx.x;
    float acc = 0.0f;
    for (int k = 0; k < T_; k++) acc += expf(-fabsf((float)(j - k)) * INV_E);
    s[j] = acc;
}

// -------------------------------- A2 bf16 [i][j] = exp(-|i-j|/e)/s[j]
__global__ void a2fill_k(const float* __restrict__ s, ushort* __restrict__ A2) {
    int i = blockIdx.x, j = threadIdx.x;
    A2[i * 256 + j] = f2b(expf(-fabsf((float)(i - j)) * INV_E) / s[j]);
}

// ------------------- LayerNorm: one wave per row, shuffle-only reductions
__global__ __launch_bounds__(256)
void ln_k(const ushort* __restrict__ X, const float* __restrict__ g,
          const float* __restrict__ b, ushort* __restrict__ Z) {
    int row  = blockIdx.x * 4 + (threadIdx.x >> 6);
    int lane = threadIdx.x & 63;
    const ushort* xr = X + (size_t)row * C_ + lane * 8;
    uint4 raw = *(const uint4*)xr;
    float f[8];
    f[0] = __uint_as_float(raw.x << 16); f[1] = __uint_as_float(raw.x & 0xffff0000u);
    f[2] = __uint_as_float(raw.y << 16); f[3] = __uint_as_float(raw.y & 0xffff0000u);
    f[4] = __uint_as_float(raw.z << 16); f[5] = __uint_as_float(raw.z & 0xffff0000u);
    f[6] = __uint_as_float(raw.w << 16); f[7] = __uint_as_float(raw.w & 0xffff0000u);
    float s = 0.0f, s2 = 0.0f;
#pragma unroll
    for (int u = 0; u < 8; u++) { s += f[u]; s2 += f[u] * f[u]; }
#pragma unroll
    for (int m = 1; m < 64; m <<= 1) {
        s  += __shfl_xor(s, m);
        s2 += __shfl_xor(s2, m);
    }
    float mean = s * (1.0f / C_);
    float var  = s2 * (1.0f / C_) - mean * mean;
    float rinv = rsqrtf(var + LEPS);
    const float* gp = g + lane * 8;
    const float* bp = b + lane * 8;
    float4 g0 = *(const float4*)gp, g1 = *(const float4*)(gp + 4);
    float4 b0 = *(const float4*)bp, b1 = *(const float4*)(bp + 4);
    uint4 outv;
    outv.x = pk((f[0]-mean)*rinv*g0.x+b0.x, (f[1]-mean)*rinv*g0.y+b0.y);
    outv.y = pk((f[2]-mean)*rinv*g0.z+b0.z, (f[3]-mean)*rinv*g0.w+b0.w);
    outv.z = pk((f[4]-mean)*rinv*g1.x+b1.x, (f[5]-mean)*rinv*g1.y+b1.y);
    outv.w = pk((f[6]-mean)*rinv*g1.z+b1.z, (f[7]-mean)*rinv*g1.w+b1.w);
    *(uint4*)(Z + (size_t)row * C_ + lane * 8) = outv;
}

// ============== bf16 MFMA GEMM, 128x128 tile, BK=32, global_load_lds ========
// C(MxN) = A(MxK,bf16) @ B'(NxK,bf16)  [+bias] [ACT 1=gelu 2=relu] [+R bf16]
// CONV=1: A implicit im2row of padded Xp ([bn][258][1024], zero pad rows)
template<int CONV, int ACT, int RESID, int OUTBF>
__global__ __launch_bounds__(256)
void gemm_k(const ushort* __restrict__ A, const ushort* __restrict__ B,
            const float* __restrict__ bias, const ushort* __restrict__ R,
            void* __restrict__ Cout, int M, int N, int K,
            const ushort* __restrict__ Xp) {
    __shared__ __align__(16) ushort As[128 * 32];
    __shared__ __align__(16) ushort Bs[128 * 32];
    const int tid  = threadIdx.x;
    const int lane = tid & 63, wave = tid >> 6;
    const int wr = wave >> 1, wc = wave & 1;
    const int lm = lane & 15, quad = lane >> 4;

    // ---- XCD-aware swizzle: all N-panels of one M-tile on one XCD ----
    const int NP = gridDim.x, My = gridDim.y;
    int m_idx, n_idx;
    if ((My & 7) == 0) {
        int bid = blockIdx.y * NP + blockIdx.x;
        m_idx = (bid & 7) + 8 * (bid / (8 * NP));
        n_idx = (bid >> 3) % NP;
    } else {
        m_idx = blockIdx.y; n_idx = blockIdx.x;
    }
    const int m0 = m_idx * 128, n0 = n_idx * 128;

    // staging geometry: wave w stages rows [w*32, w*32+32), 16 rows per DMA issue
    const int srow   = lane >> 2;        // 0..15
    const int schunk = (lane & 3) * 8;   // k offset (elems)
    ushort* AsW = As + wave * 32 * 32;
    ushort* BsW = Bs + wave * 32 * 32;

    f32x4 acc[4][4];
#pragma unroll
    for (int mt = 0; mt < 4; mt++)
#pragma unroll
        for (int nt = 0; nt < 4; nt++) acc[mt][nt] = (f32x4){0.f, 0.f, 0.f, 0.f};

    for (int k0 = 0; k0 < K; k0 += 32) {
        // ---- stage A (128x32) ----
        if (CONV) {
            int dt = k0 >> 10;
            int ci = (k0 & 1023) + schunk;
            int g0 = m0 + wave * 32 + srow;
            int bn0 = g0 >> 8, t0 = g0 & 255;
            int g1 = g0 + 16;
            int bn1 = g1 >> 8, t1 = g1 & 255;
            gl2lds(Xp + (size_t)bn0 * XROW + (t0 + dt) * 1024 + ci, AsW);
            gl2lds(Xp + (size_t)bn1 * XROW + (t1 + dt) * 1024 + ci, AsW + 16 * 32);
        } else {
            const ushort* ga = A + (size_t)(m0 + wave * 32 + srow) * K + k0 + schunk;
            gl2lds(ga, AsW);
            gl2lds(ga + (size_t)16 * K, AsW + 16 * 32);
        }
        // ---- stage B (128x32), B pre-transposed [N][K] ----
        {
            const ushort* gb = B + (size_t)(n0 + wave * 32 + srow) * K + k0 + schunk;
            gl2lds(gb, BsW);
            gl2lds(gb + (size_t)16 * K, BsW + 16 * 32);
        }
        __syncthreads();
        short8 af[4], bfv[4];
#pragma unroll
        for (int mt = 0; mt < 4; mt++)
            af[mt] = *(const short8*)&As[(wr * 64 + mt * 16 + lm) * 32 + quad * 8];
#pragma unroll
        for (int nt = 0; nt < 4; nt++)
            bfv[nt] = *(const short8*)&Bs[(wc * 64 + nt * 16 + lm) * 32 + quad * 8];
#pragma unroll
        for (int mt = 0; mt < 4; mt++)
#pragma unroll
            for (int nt = 0; nt < 4; nt++)
                acc[mt][nt] = __builtin_amdgcn_mfma_f32_16x16x32_bf16(
                    af[mt], bfv[nt], acc[mt][nt], 0, 0, 0);
        __syncthreads();
    }

#pragma unroll
    for (int mt = 0; mt < 4; mt++) {
        int grow0 = m0 + wr * 64 + mt * 16 + quad * 4;
#pragma unroll
        for (int nt = 0; nt < 4; nt++) {
            int gcol = n0 + wc * 64 + nt * 16 + lm;
            float bia = bias ? bias[gcol] : 0.0f;
            f32x4 v = acc[mt][nt];
#pragma unroll
            for (int i = 0; i < 4; i++) {
                int grow = grow0 + i;
                float val = v[i] + bia;
                if (ACT == 1) val = val * 0.5f * (1.0f + erff(val * 0.70710678118654752f));
                if (ACT == 2) val = fmaxf(val, 0.0f);
                if (RESID) val += b2f(R[(size_t)grow * N + gcol]);
                if (OUTBF) ((ushort*)Cout)[(size_t)grow * N + gcol] = f2b(val);
                else       ((float*)Cout)[(size_t)grow * N + gcol]  = val;
            }
        }
    }
}

// ================= flash-style softmax attention (o1 half), MFMA ============
__global__ __launch_bounds__(256)
void attn1_k(const ushort* __restrict__ qkvt, ushort* __restrict__ O) {
    const int bn = blockIdx.x, h = blockIdx.y;
    const int tid = threadIdx.x;
    const int wave = tid >> 6, lane = tid & 63;
    const int lm = lane & 15, quad = lane >> 4;
    __shared__ __align__(16) ushort Ks[32 * 136];
    __shared__ __align__(16) ushort Vt[128 * 40];
    __shared__ __align__(16) ushort Ps[4][64 * 40];
    const ushort* base = qkvt + (size_t)bn * T_ * 2048;

    short8 aq[4][4];
#pragma unroll
    for (int mt = 0; mt < 4; mt++) {
        const ushort* qrow = base + (size_t)(wave * 64 + mt * 16 + lm) * 2048 + h * DH_;
#pragma unroll
        for (int ks = 0; ks < 4; ks++)
            aq[mt][ks] = *(const short8*)(qrow + ks * 32 + quad * 8);
    }

    f32x4 oacc[4][8];
#pragma unroll
    for (int mt = 0; mt < 4; mt++)
#pragma unroll
        for (int nt = 0; nt < 8; nt++) oacc[mt][nt] = (f32x4){0.f, 0.f, 0.f, 0.f};
    float mrow[4][4], lrow[4][4];
#pragma unroll
    for (int mt = 0; mt < 4; mt++)
#pragma unroll
        for (int i = 0; i < 4; i++) { mrow[mt][i] = -1e30f; lrow[mt][i] = 0.0f; }

    for (int kt = 0; kt < 8; kt++) {
        __syncthreads();
#pragma unroll
        for (int u = 0; u < 2; u++) {
            int ii = tid + u * 256;
            int j = ii >> 4, dc = ii & 15;
            *(uint4*)&Ks[j * 136 + dc * 8] =
                *(const uint4*)(base + (size_t)(kt * 32 + j) * 2048 + 512 + h * DH_ + dc * 8);
        }
        {
            int j = tid & 31, half = tid >> 5;
            const ushort* vrow = base + (size_t)(kt * 32 + j) * 2048 + 1024 + h * DH_ + half * 16;
            uint4 v0 = *(const uint4*)vrow;
            uint4 v1 = *(const uint4*)(vrow + 8);
            ushort e[16];
            *(uint4*)&e[0] = v0; *(uint4*)&e[8] = v1;
#pragma unroll
            for (int u = 0; u < 16; u++)
                Vt[(half * 16 + u) * 40 + j] = e[u];
        }
        __syncthreads();

        f32x4 s[4][2];
#pragma unroll
        for (int mt = 0; mt < 4; mt++)
#pragma unroll
            for (int nt = 0; nt < 2; nt++) s[mt][nt] = (f32x4){0.f, 0.f, 0.f, 0.f};
#pragma unroll
        for (int ks = 0; ks < 4; ks++) {
            short8 bk0 = *(const short8*)&Ks[lm * 136 + ks * 32 + quad * 8];
            short8 bk1 = *(const short8*)&Ks[(16 + lm) * 136 + ks * 32 + quad * 8];
#pragma unroll
            for (int mt = 0; mt < 4; mt++) {
                s[mt][0] = __builtin_amdgcn_mfma_f32_16x16x32_bf16(aq[mt][ks], bk0, s[mt][0], 0, 0, 0);
                s[mt][1] = __builtin_amdgcn_mfma_f32_16x16x32_bf16(aq[mt][ks], bk1, s[mt][1], 0, 0, 0);
            }
        }

#pragma unroll
        for (int mt = 0; mt < 4; mt++) {
#pragma unroll
            for (int i = 0; i < 4; i++) {
                float v0 = s[mt][0][i] * SCALE_;
                float v1 = s[mt][1][i] * SCALE_;
                float rmax = fmaxf(v0, v1);
#pragma unroll
                for (int mk = 1; mk < 16; mk <<= 1)
                    rmax = fmaxf(rmax, __shfl_xor(rmax, mk));
                float mold = mrow[mt][i];
                float mnew = fmaxf(mold, rmax);
                float alpha = __expf(mold - mnew);
                float p0 = __expf(v0 - mnew);
                float p1 = __expf(v1 - mnew);
                float rs = p0 + p1;
#pragma unroll
                for (int mk = 1; mk < 16; mk <<= 1)
                    rs += __shfl_xor(rs, mk);
                lrow[mt][i] = lrow[mt][i] * alpha + rs;
                mrow[mt][i] = mnew;
#pragma unroll
                for (int nt = 0; nt < 8; nt++) {
                    oacc[mt][nt][i] *= alpha;
                }
                int prow = mt * 16 + quad * 4 + i;
                Ps[wave][prow * 40 + lm]      = f2b(p0);
                Ps[wave][prow * 40 + 16 + lm] = f2b(p1);
            }
        }

        short8 ap[4];
#pragma unroll
        for (int mt = 0; mt < 4; mt++)
            ap[mt] = *(const short8*)&Ps[wave][(mt * 16 + lm) * 40 + quad * 8];
#pragma unroll
        for (int nt = 0; nt < 8; nt++) {
            short8 bv = *(const short8*)&Vt[(nt * 16 + lm) * 40 + quad * 8];
#pragma unroll
            for (int mt = 0; mt < 4; mt++)
                oacc[mt][nt] = __builtin_amdgcn_mfma_f32_16x16x32_bf16(ap[mt], bv, oacc[mt][nt], 0, 0, 0);
        }
    }

#pragma unroll
    for (int mt = 0; mt < 4; mt++) {
#pragma unroll
        for (int i = 0; i < 4; i++) {
            int row = wave * 64 + mt * 16 + quad * 4 + i;
            float rinv = 1.0f / lrow[mt][i];
#pragma unroll
            for (int nt = 0; nt < 8; nt++) {
                int d = nt * 16 + lm;
                O[((size_t)bn * T_ + row) * 1024 + h * 256 + d] =
                    f2b(oacc[mt][nt][i] * rinv);
            }
        }
    }
}

// ================= decay attention (o2 half): o2 = A2 @ T, batched over bn ==
__global__ __launch_bounds__(256)
void attn2_k(const ushort* __restrict__ A2, const ushort* __restrict__ qkvt,
             ushort* __restrict__ O) {
    __shared__ __align__(16) ushort As[128 * LDT];
    __shared__ __align__(16) ushort Bs[128 * 48];
    const int tid = threadIdx.x;
    const int bn = blockIdx.z;
    const int m0 = blockIdx.y * 128;
    const int n0 = blockIdx.x * 128;
    const int lane = tid & 63, wave = tid >> 6;
    const int wr = wave >> 1, wc = wave & 1;
    const int lm = lane & 15, quad = lane >> 4;
    const ushort* tbase = qkvt + (size_t)bn * T_ * 2048 + 1536;
    const int r = tid >> 1, c0 = (tid & 1) * 2;

    f32x4 acc[4][4];
#pragma unroll
    for (int mt = 0; mt < 4; mt++)
#pragma unroll
        for (int nt = 0; nt < 4; nt++) acc[mt][nt] = (f32x4){0.f, 0.f, 0.f, 0.f};

    for (int k0 = 0; k0 < 256; k0 += 32) {
        const ushort* Arow = A2 + (size_t)(m0 + r) * 256 + k0;
        *(uint4*)&As[r * LDT + c0 * 8]       = *(const uint4*)(Arow + c0 * 8);
        *(uint4*)&As[r * LDT + (c0 + 1) * 8] = *(const uint4*)(Arow + (c0 + 1) * 8);
        {
            int kr = tid & 31, np = tid >> 5;
            const ushort* trow = tbase + (size_t)(k0 + kr) * 2048 + n0 + np * 16;
            uint4 v0 = *(const uint4*)trow;
            uint4 v1 = *(const uint4*)(trow + 8);
            ushort e[16];
            *(uint4*)&e[0] = v0; *(uint4*)&e[8] = v1;
#pragma unroll
            for (int u = 0; u < 16; u++)
                Bs[(np * 16 + u) * 48 + kr] = e[u];
        }
        __syncthreads();
        short8 af[4], bf[4];
#pragma unroll
        for (int mt = 0; mt < 4; mt++)
            af[mt] = *(const short8*)&As[(wr * 64 + mt * 16 + lm) * LDT + quad * 8];
#pragma unroll
        for (int nt = 0; nt < 4; nt++)
            bf[nt] = *(const short8*)&Bs[(wc * 64 + nt * 16 + lm) * 48 + quad * 8];
#pragma unroll
        for (int mt = 0; mt < 4; mt++)
#pragma unroll
            for (int nt = 0; nt < 4; nt++)
                acc[mt][nt] = __builtin_amdgcn_mfma_f32_16x16x32_bf16(
                    af[mt], bf[nt], acc[mt][nt], 0, 0, 0);
        __syncthreads();
    }

#pragma unroll
    for (int mt = 0; mt < 4; mt++) {
        int row0 = m0 + wr * 64 + mt * 16 + quad * 4;
#pragma unroll
        for (int nt = 0; nt < 4; nt++) {
            int n = n0 + wc * 64 + nt * 16 + lm;
            int h = n >> 7, d = n & 127;
#pragma unroll
            for (int i = 0; i < 4; i++) {
                int row = row0 + i;
                O[((size_t)bn * T_ + row) * 1024 + h * 256 + 128 + d] =
                    f2b(acc[mt][nt][i]);
            }
        }
    }
}

// ============ head stage 1: x1 = h @ c1W^T + c1b  (M x 32, K=512, MFMA) =====
#define BLD 520
__global__ __launch_bounds__(256)
void head1_k(const ushort* __restrict__ Hb, const ushort* __restrict__ c1Wb,
             const float* __restrict__ c1b, float* __restrict__ X1) {
    __shared__ __align__(16) ushort As[128 * LDT];
    __shared__ __align__(16) ushort Bs[32 * BLD];
    const int tid = threadIdx.x;
    const int lane = tid & 63, wave = tid >> 6;
    const int lm = lane & 15, quad = lane >> 4;
    const int m0 = blockIdx.x * 128;
#pragma unroll
    for (int u = 0; u < 8; u++) {
        int ii = tid + u * 256;
        int nrow = ii >> 6;
        int koff = (ii & 63) * 8;
        *(uint4*)&Bs[nrow * BLD + koff] = *(const uint4*)(c1Wb + nrow * 512 + koff);
    }
    f32x4 acc[2][2];
#pragma unroll
    for (int mt = 0; mt < 2; mt++)
#pragma unroll
        for (int nt = 0; nt < 2; nt++) acc[mt][nt] = (f32x4){0.f, 0.f, 0.f, 0.f};

    const int r = tid >> 1, half = tid & 1;
    for (int k0 = 0; k0 < 512; k0 += 32) {
        const ushort* s = Hb + (size_t)(m0 + r) * 512 + k0 + half * 16;
        uint4 v0 = *(const uint4*)s;
        uint4 v1 = *(const uint4*)(s + 8);
        __syncthreads();
        *(uint4*)&As[r * LDT + half * 16]     = v0;
        *(uint4*)&As[r * LDT + half * 16 + 8] = v1;
        __syncthreads();
        short8 af[2], bf[2];
#pragma unroll
        for (int mt = 0; mt < 2; mt++)
            af[mt] = *(const short8*)&As[(wave * 32 + mt * 16 + lm) * LDT + quad * 8];
#pragma unroll
        for (int nt = 0; nt < 2; nt++)
            bf[nt] = *(const short8*)&Bs[(nt * 16 + lm) * BLD + k0 + quad * 8];
#pragma unroll
        for (int mt = 0; mt < 2; mt++)
#pragma unroll
            for (int nt = 0; nt < 2; nt++)
                acc[mt][nt] = __builtin_amdgcn_mfma_f32_16x16x32_bf16(
                    af[mt], bf[nt], acc[mt][nt], 0, 0, 0);
    }
#pragma unroll
    for (int mt = 0; mt < 2; mt++) {
        int row0 = m0 + wave * 32 + mt * 16 + quad * 4;
#pragma unroll
        for (int nt = 0; nt < 2; nt++) {
            int col = nt * 16 + lm;
            float bia = c1b[col];
#pragma unroll
            for (int i = 0; i < 4; i++)
                X1[(size_t)(row0 + i) * 32 + col] = acc[mt][nt][i] + bia;
        }
    }
}

// ============ head stage 2: one thread per (bn,t) row ========================
__global__ __launch_bounds__(256)
void head2_k(const float* __restrict__ X1, int bn_base, int M,
             const float* __restrict__ g1, const float* __restrict__ b1,
             const float* __restrict__ m1, const float* __restrict__ v1,
             const float* __restrict__ c2W, const float* __restrict__ c2b,
             const float* __restrict__ g2, const float* __restrict__ b2,
             const float* __restrict__ m2, const float* __restrict__ v2,
             const float* __restrict__ c3W, const float* __restrict__ c3b,
             float* __restrict__ sum_dist, float* __restrict__ sum_score) {
    int row = blockIdx.x * 256 + threadIdx.x;
    if (row >= M) return;
    float x1[32], y1[32];
    const float* xr = X1 + (size_t)row * 32;
#pragma unroll
    for (int c = 0; c < 32; c++) x1[c] = xr[c];
    float d1 = 0.0f;
#pragma unroll
    for (int c = 0; c < 32; c++) {
        float dd = x1[c] - m1[c];
        d1 += dd * dd / v1[c];
        y1[c] = fmaxf(0.0f, dd * rsqrtf(v1[c] + LEPS) * g1[c] + b1[c]);
    }
    float d2 = 0.0f, sc = c3b[0];
#pragma unroll
    for (int o = 0; o < 16; o++) {
        float acc = c2b[o];
        const float* wr = c2W + o * 32;
#pragma unroll
        for (int c = 0; c < 32; c++) acc += wr[c] * y1[c];
        float dd = acc - m2[o];
        d2 += dd * dd / v2[o];
        float y2 = fmaxf(0.0f, dd * rsqrtf(v2[o] + LEPS) * g2[o] + b2[o]);
        sc += c3W[o] * y2;
    }
    float dist = sqrtf(d1) + sqrtf(d2);
    sc = 1.0f / (1.0f + expf(-sc));
    int bn = bn_base + (row >> 8);
    int t = row & 255;
    int b = bn / 10;
    atomicAdd(&sum_dist[b * T_ + t], dist);
    atomicAdd(&sum_score[b * T_ + t], sc);
}

// --------------------------------------------------------------- final out
__global__ void combine_k(const float* __restrict__ sd, const float* __restrict__ ss,
                          float* __restrict__ out) {
    int i = blockIdx.x * 256 + threadIdx.x;
    if (i < 16 * T_) out[i] = (sd[i] * 0.1f) * (ss[i] * 0.1f);
}

// ===========================================================================
extern "C" void kernel_launch(void* const* d_in, const int* in_sizes, int n_in,
                              void* d_out, int out_size, void* d_ws, size_t ws_size,
                              hipStream_t stream) {
    const float* x     = (const float*)d_in[0];
    const float* W_emb = (const float*)d_in[1];
    const float* b_emb = (const float*)d_in[2];
    const float* ln1_g = (const float*)d_in[3];
    const float* ln1_b = (const float*)d_in[4];
    const float* W_qkv = (const float*)d_in[5];
    const float* W_o   = (const float*)d_in[6];
    const float* b_o   = (const float*)d_in[7];
    const float* ln2_g = (const float*)d_in[8];
    const float* ln2_b = (const float*)d_in[9];
    const float* W_f1  = (const float*)d_in[10];
    const float* b_f1  = (const float*)d_in[11];
    const float* W_f2  = (const float*)d_in[12];
    const float* b_f2  = (const float*)d_in[13];
    const float* c1_W  = (const float*)d_in[14];
    const float* c1_b  = (const float*)d_in[15];
    const float* bn1_g = (const float*)d_in[16];
    const float* bn1_b = (const float*)d_in[17];
    const float* bn1_m = (const float*)d_in[18];
    const float* bn1_v = (const float*)d_in[19];
    const float* c2_W  = (const float*)d_in[20];
    const float* c2_b  = (const float*)d_in[21];
    const float* bn2_g = (const float*)d_in[22];
    const float* bn2_b = (const float*)d_in[23];
    const float* bn2_m = (const float*)d_in[24];
    const float* bn2_v = (const float*)d_in[25];
    const float* c3_W  = (const float*)d_in[26];
    const float* c3_b  = (const float*)d_in[27];
    float* out = (float*)d_out;

    // ---------------- workspace layout (runtime-chunked over bn) ----------
    char* p = (char*)d_ws;
    auto alloc = [&](size_t bytes) -> char* {
        char* q = p; p += (bytes + 255) & ~(size_t)255; return q;
    };
    ushort* wEmb = (ushort*)alloc((size_t)C_ * 3072 * 2);
    ushort* wQkv = (ushort*)alloc((size_t)2 * 2048 * 512 * 2);
    ushort* wO   = (ushort*)alloc((size_t)2 * 512 * 1024 * 2);
    ushort* wF1  = (ushort*)alloc((size_t)2 * 512 * 512 * 2);
    ushort* wF2  = (ushort*)alloc((size_t)2 * 512 * 512 * 2);
    ushort* A2bf = (ushort*)alloc((size_t)256 * 256 * 2);
    ushort* c1Wb = (ushort*)alloc((size_t)32 * 512 * 2);
    float*  s256      = (float*)alloc(256 * 4);
    float*  sum_dist  = (float*)alloc(4096 * 4);
    float*  sum_score = (float*)alloc(4096 * 4);
    size_t fixedB = (size_t)(p - (char*)d_ws);

    // per-row bytes: xbp 2064 + h 1024 + z 1024 + qkvt 4096 + o 2048 + X1 128 = 10384
    int CH = 8;
    const int cands[7] = {160, 80, 40, 32, 20, 16, 10};
    for (int ci = 0; ci < 7; ci++) {
        size_t per = (size_t)cands[ci] * 256 * 10384 + 16384;
        if (fixedB + per <= ws_size) { CH = cands[ci]; break; }
    }
    const int MR = CH * 256;
    ushort* xbp  = (ushort*)alloc((size_t)CH * XROW * 2);
    ushort* h    = (ushort*)alloc((size_t)MR * 512 * 2);
    ushort* z    = (ushort*)alloc((size_t)MR * 512 * 2);
    ushort* qkvt = (ushort*)alloc((size_t)MR * 2048 * 2);
    ushort* o    = (ushort*)alloc((size_t)MR * 1024 * 2);
    ushort* g    = o;
    float*  X1   = (float*)alloc((size_t)MR * 32 * 4);

    // ---------------- once-per-launch prep ----------------
    zero_k<<<(8192 + 255) / 256, 256, 0, stream>>>(sum_dist, 8192);
    a2_colsum_k<<<1, 256, 0, stream>>>(s256);
    a2fill_k<<<256, 256, 0, stream>>>(s256, A2bf);
    wemb_k<<<(C_ * 3072 + 255) / 256, 256, 0, stream>>>(W_emb, wEmb);
    bcvt_k<<<(32 * 512 + 255) / 256, 256, 0, stream>>>(c1_W, c1Wb, 32 * 512);
    for (int l = 0; l < 2; l++) {
        tconv_k<<<dim3(512 / 32, 2048 / 32), 256, 0, stream>>>(
            W_qkv + (size_t)l * 512 * 2048, wQkv + (size_t)l * 2048 * 512, 512, 2048);
        tconv_k<<<dim3(1024 / 32, 512 / 32), 256, 0, stream>>>(
            W_o + (size_t)l * 1024 * 512, wO + (size_t)l * 512 * 1024, 1024, 512);
        tconv_k<<<dim3(512 / 32, 512 / 32), 256, 0, stream>>>(
            W_f1 + (size_t)l * 512 * 512, wF1 + (size_t)l * 512 * 512, 512, 512);
        tconv_k<<<dim3(512 / 32, 512 / 32), 256, 0, stream>>>(
            W_f2 + (size_t)l * 512 * 512, wF2 + (size_t)l * 512 * 512, 512, 512);
    }

    // ---------------- pipeline, chunked over bn ----------------
    for (int cs = 0; cs < BNB; cs += CH) {
        const float* xc = x + (size_t)cs * T_ * D_;

        // x chunk -> bf16 padded + zero pad rows
        int n4 = MR * 1024 / 4;
        xcvt_k<<<(n4 + 255) / 256, 256, 0, stream>>>(xc, xbp, n4);
        xpad_k<<<(CH * 1024 + 255) / 256, 256, 0, stream>>>(xbp, CH);

        // conv1d(k=3,pad=1)+ReLU as implicit-im2row MFMA GEMM -> h bf16
        gemm_k<1, 2, 0, 1><<<dim3(512 / 128, MR / 128), 256, 0, stream>>>(
            nullptr, wEmb, b_emb, nullptr, h, MR, 512, 3072, xbp);

        for (int l = 0; l < 2; l++) {
            ln_k<<<MR / 4, 256, 0, stream>>>(h, ln1_g + l * C_, ln1_b + l * C_, z);
            gemm_k<0, 0, 0, 1><<<dim3(2048 / 128, MR / 128), 256, 0, stream>>>(
                z, wQkv + (size_t)l * 2048 * 512, nullptr, nullptr, qkvt,
                MR, 2048, 512, nullptr);
            attn1_k<<<dim3(CH, H_), 256, 0, stream>>>(qkvt, o);
            attn2_k<<<dim3(4, 2, CH), 256, 0, stream>>>(A2bf, qkvt, o);
            gemm_k<0, 0, 1, 1><<<dim3(512 / 128, MR / 128), 256, 0, stream>>>(
                o, wO + (size_t)l * 512 * 1024, b_o + l * C_, h, h,
                MR, 512, 1024, nullptr);
            ln_k<<<MR / 4, 256, 0, stream>>>(h, ln2_g + l * C_, ln2_b + l * C_, z);
            gemm_k<0, 1, 0, 1><<<dim3(512 / 128, MR / 128), 256, 0, stream>>>(
                z, wF1 + (size_t)l * 512 * 512, b_f1 + l * C_, nullptr, g,
                MR, 512, 512, nullptr);
            gemm_k<0, 0, 1, 1><<<dim3(512 / 128, MR / 128), 256, 0, stream>>>(
                g, wF2 + (size_t)l * 512 * 512, b_f2 + l * C_, h, h,
                MR, 512, 512, nullptr);
        }

        head1_k<<<MR / 128, 256, 0, stream>>>(h, c1Wb, c1_b, X1);
        head2_k<<<MR / 256, 256, 0, stream>>>(
            X1, cs, MR, bn1_g, bn1_b, bn1_m, bn1_v,
            c2_W, c2_b, bn2_g, bn2_b, bn2_m, bn2_v, c3_W, c3_b,
            sum_dist, sum_score);
    }

    combine_k<<<16, 256, 0, stream>>>(sum_dist, sum_score, out);
}